// Round 1
// 176.211 us; speedup vs baseline: 1.0671x; 1.0671x over previous
//
#include <hip/hip_runtime.h>

// B=8, C=128, H=W=64, G=8, K=9, Cg=16, Cd=64. NCHW, HW=4096.
// MFMA conventions (verified in-problem, round 2):
//   A-frag: lane&15 = m, k-octet = (lane>>4)*8 + j
//   B-frag: lane&15 = n, k-octet = (lane>>4)*8 + j
//   C/D:    col = lane&15 (n), row = (lane>>4)*4 + r (m)
//
// Round-4 change: k12 and k_omdcn moved to 512-thread blocks (8 waves).
// Work split K-wise (conv, dcn) / N-wise (GEMMs) so total LDS/VMEM traffic is
// unchanged; resident waves/CU double 8 -> 16 to hide gather/L2 latency.

typedef __attribute__((ext_vector_type(8))) short short8;
typedef __attribute__((ext_vector_type(4))) float f32x4;
typedef _Float16 __attribute__((ext_vector_type(2))) h2;

static __device__ __forceinline__ unsigned short f2bf(float x) {
    union { float f; unsigned int u; } v; v.f = x;
    return (unsigned short)((v.u + 0x7FFF + ((v.u >> 16) & 1)) >> 16);  // RNE
}
static __device__ __forceinline__ unsigned short f2h(float x) {
    union { _Float16 h; unsigned short u; } v; v.h = (_Float16)x;
    return v.u;
}

// ---------------- feat_s -> pixel-major bf16 fsT + f16 fsH
__global__ __launch_bounds__(256) void k_prepfs(const float* __restrict__ fs,
        uint4* __restrict__ fsT4, uint4* __restrict__ fsH4) {
    __shared__ unsigned short st[64 * 136];
    unsigned int* st32 = (unsigned int*)st;
    const int t = threadIdx.x;
    const int b = blockIdx.x >> 4;
    const int p0 = (blockIdx.x & 15) << 6;
    for (int i = t; i < 64 * 64; i += 256) {
        int c2 = i >> 6, px = i & 63;
        float v0 = fs[(((b << 7) + 2 * c2) << 10) + p0 + px];
        float v1 = fs[(((b << 7) + 2 * c2 + 1) << 10) + p0 + px];
        st32[px * 68 + c2] = (unsigned int)f2bf(v0) | ((unsigned int)f2bf(v1) << 16);
    }
    __syncthreads();
    for (int i = t; i < 64 * 16; i += 256) {
        int px = i >> 4, q = i & 15;
        fsT4[(((b << 10) + p0 + px) << 4) + q] = ((const uint4*)(st + px * 136))[q];
    }
    __syncthreads();
    for (int i = t; i < 64 * 64; i += 256) {
        int c2 = i >> 6, px = i & 63;
        float v0 = fs[(((b << 7) + 2 * c2) << 10) + p0 + px];
        float v1 = fs[(((b << 7) + 2 * c2 + 1) << 10) + p0 + px];
        st32[px * 68 + c2] = (unsigned int)f2h(v0) | ((unsigned int)f2h(v1) << 16);
    }
    __syncthreads();
    for (int i = t; i < 64 * 16; i += 256) {
        int px = i >> 4, q = i & 15;
        fsH4[(((b << 10) + p0 + px) << 4) + q] = ((const uint4*)(st + px * 136))[q];
    }
}

// ---------------- all weight packs in ONE kernel
// segments (uint4 units): wbfsm 2048 | wboff 4096 | wbcat 1024 | wbdcn 9216 (f16!) | wb2 36864
__global__ __launch_bounds__(256) void k_packall(
        const float* __restrict__ W_fsm, const float* __restrict__ W_off,
        const float* __restrict__ W_cat, const float* __restrict__ W_dcn,
        const float* __restrict__ W_om,
        unsigned short* __restrict__ wbfsm, unsigned short* __restrict__ wboff,
        unsigned short* __restrict__ wbcat, unsigned short* __restrict__ wbdcn,
        unsigned short* __restrict__ wb2) {
    int idx = blockIdx.x * 256 + threadIdx.x;
    int lane = idx & 63;
    int ml = lane & 15, kl = (lane >> 4) * 8;
    unsigned short tmp[8];
    if (idx < 2048) {                       // wbfsm: K=128, NT=8 (bf16)
        int r = idx >> 6;
        int o = (r % 8) * 16 + ml, k0 = (r / 8) * 32 + kl;
#pragma unroll
        for (int j = 0; j < 8; j++) tmp[j] = f2bf(W_fsm[o * 128 + k0 + j]);
        ((uint4*)wbfsm)[idx] = *(const uint4*)tmp;
    } else if (idx < 6144) {                // wboff: K=256, NT=8, x2 for k>=128 (bf16)
        int i2 = idx - 2048;
        int r = i2 >> 6;
        int o = (r % 8) * 16 + ml, k0 = (r / 8) * 32 + kl;
#pragma unroll
        for (int j = 0; j < 8; j++) {
            int k = k0 + j;
            float f = W_off[o * 256 + k];
            if (k >= 128) f *= 2.0f;
            tmp[j] = f2bf(f);
        }
        ((uint4*)wboff)[i2] = *(const uint4*)tmp;
    } else if (idx < 7168) {                // wbcat: K=64, NT=8 (bf16)
        int i2 = idx - 6144;
        int r = i2 >> 6;
        int o = (r % 8) * 16 + ml, k0 = (r / 8) * 32 + kl;
#pragma unroll
        for (int j = 0; j < 8; j++) tmp[j] = f2bf(W_cat[o * 64 + k0 + j]);
        ((uint4*)wbcat)[i2] = *(const uint4*)tmp;
    } else if (idx < 16384) {               // wbdcn: K=1152 (g,tap,c), NT=4 (f16)
        int i2 = idx - 7168;
        int r = i2 >> 6;
        int o = (r & 3) * 16 + ml, k0 = (r >> 2) * 32 + kl;
#pragma unroll
        for (int j = 0; j < 8; j++) {
            int k = k0 + j;
            int g = k / 144;
            int rem = k - g * 144;
            tmp[j] = f2h(W_dcn[(o * 128 + g * 16 + (rem & 15)) * 9 + (rem >> 4)]);
        }
        ((uint4*)wbdcn)[i2] = *(const uint4*)tmp;
    } else if (idx < 53248) {               // wb2: K=(tap,c), NT=16 (N=256, pad o>=216) bf16
        int i2 = idx - 16384;
        int r = i2 >> 6;
        int nt = r & 15, kk = r >> 4;
        int tap = kk >> 2, cc = kk & 3;
        int o = nt * 16 + ml;
        int c0 = cc * 32 + kl;
#pragma unroll
        for (int j = 0; j < 8; j++) {
            float v = (o < 216) ? W_om[(o * 128 + (c0 + j)) * 9 + tap] : 0.0f;
            tmp[j] = f2bf(v);
        }
        ((uint4*)wb2)[i2] = *(const uint4*)tmp;
    }
}

// ---------------- k12: fused fsm GEMM (K=128) + off GEMM (K=256)
// 512 blocks x 8 waves. wave = (pq = px-quarter, nh = N-half). Each wave does
// 16 px x 64 out per GEMM (N-split); A reads double (trivial), B reads unchanged.
__global__ __launch_bounds__(512, 4) void k12(const float* __restrict__ feat_l,
        const uint4* __restrict__ fsT4,
        const unsigned short* __restrict__ wbf, const unsigned short* __restrict__ wbo,
        const float* __restrict__ s_fsm, const float* __restrict__ b_fsm,
        const float* __restrict__ s_off, const float* __restrict__ b_off,
        float* __restrict__ feat_arm, unsigned short* __restrict__ offT) {
    __shared__ unsigned short A1[64 * 136];
    __shared__ unsigned short A2[64 * 264];
    float* E32 = (float*)A1;
    const int t = threadIdx.x;
    const int b = blockIdx.x >> 6;
    const int h = blockIdx.x & 63;
    const int hw0 = h << 6;
    unsigned int* A1w = (unsigned int*)A1;
    for (int i = t; i < 64 * 64; i += 512) {
        int c2 = i >> 6, px = i & 63;
        float v0 = feat_l[(((b << 7) + 2 * c2) << 12) + hw0 + px];
        float v1 = feat_l[(((b << 7) + 2 * c2 + 1) << 12) + hw0 + px];
        A1w[px * 68 + c2] = (unsigned int)f2bf(v0) | ((unsigned int)f2bf(v1) << 16);
    }
    {
        const int h2 = h >> 1;
        // 512 threads, 512 items: one each
        int px2 = t >> 4, q = t & 15;
        uint4 v = fsT4[(((b << 10) + (h2 << 5) + px2) << 4) + q];
        ((uint4*)(A2 + (2 * px2) * 264 + 128))[q] = v;
        ((uint4*)(A2 + (2 * px2 + 1) * 264 + 128))[q] = v;
    }
    __syncthreads();
    const int lane = t & 63;
    const int w = __builtin_amdgcn_readfirstlane(t >> 6);
    const int pq = w & 3;    // px quarter
    const int nh = w >> 2;   // N half
    const int m = lane & 15, ko = lane >> 4;
    f32x4 acc[4];
#pragma unroll
    for (int nt2 = 0; nt2 < 4; nt2++) acc[nt2] = (f32x4){0.f, 0.f, 0.f, 0.f};
#pragma unroll
    for (int kk = 0; kk < 4; kk++) {
        short8 av = *(const short8*)(A1 + (pq * 16 + m) * 136 + kk * 32 + ko * 8);
        const uint4* wb = (const uint4*)wbf + (kk * 8 + nh * 4) * 64 + lane;
#pragma unroll
        for (int nt2 = 0; nt2 < 4; nt2++) {
            uint4 bu = wb[nt2 * 64];
            acc[nt2] = __builtin_amdgcn_mfma_f32_16x16x32_bf16(av, *(short8*)&bu, acc[nt2], 0, 0, 0);
        }
    }
#pragma unroll
    for (int nt2 = 0; nt2 < 4; nt2++) {
        int o = ((nh << 2) + nt2) * 16 + m;
        float sc = s_fsm[o], bi = b_fsm[o];
#pragma unroll
        for (int r = 0; r < 4; r++) {
            float v = fmaf(acc[nt2][r], sc, bi);
            v = v > 0.f ? v : 0.f;
            acc[nt2][r] = v;
            A2[(pq * 16 + ko * 4 + r) * 264 + o] = f2bf(v);
        }
    }
#pragma unroll 1
    for (int half = 0; half < 2; half++) {
        __syncthreads();
        if (nh == half) {
#pragma unroll
            for (int nt2 = 0; nt2 < 4; nt2++)
#pragma unroll
                for (int r = 0; r < 4; r++)
                    E32[(pq * 16 + ko * 4 + r) * 67 + nt2 * 16 + m] = acc[nt2][r];
        }
        __syncthreads();
        for (int i = t; i < 4096; i += 512) {
            int ol = i >> 6, pp = i & 63;
            feat_arm[(((b << 7) + half * 64 + ol) << 12) + hw0 + pp] = E32[pp * 67 + ol];
        }
    }
    __syncthreads();
    f32x4 acc2[4];
#pragma unroll
    for (int nt2 = 0; nt2 < 4; nt2++) acc2[nt2] = (f32x4){0.f, 0.f, 0.f, 0.f};
#pragma unroll
    for (int kk = 0; kk < 8; kk++) {
        short8 av = *(const short8*)(A2 + (pq * 16 + m) * 264 + kk * 32 + ko * 8);
        const uint4* wb = (const uint4*)wbo + (kk * 8 + nh * 4) * 64 + lane;
#pragma unroll
        for (int nt2 = 0; nt2 < 4; nt2++) {
            uint4 bu = wb[nt2 * 64];
            acc2[nt2] = __builtin_amdgcn_mfma_f32_16x16x32_bf16(av, *(short8*)&bu, acc2[nt2], 0, 0, 0);
        }
    }
    __syncthreads();
#pragma unroll
    for (int nt2 = 0; nt2 < 4; nt2++) {
        int o = ((nh << 2) + nt2) * 16 + m;
        float sc = s_off[o], bi = b_off[o];
#pragma unroll
        for (int r = 0; r < 4; r++) {
            float v = fmaf(acc2[nt2][r], sc, bi);
            v = v > 0.f ? v : 0.f;
            A2[(pq * 16 + ko * 4 + r) * 264 + o] = f2bf(v);
        }
    }
    __syncthreads();
    for (int i = t; i < 64 * 16; i += 512) {
        int px = i >> 4, q = i & 15;
        ((uint4*)offT)[(((b << 12) + hw0 + px) << 4) + q] = ((const uint4*)(A2 + px * 264))[q];
    }
}

// ---------------- k_omdcn: FUSED conv3x3(om) -> LDS -> DCNv2 sample -> cat GEMM -> feat
// 512 blocks (b, row h) x 8 waves (512 threads).
// Phase 1 (conv): wave = (nq = N-quarter, kh = K-half of 36 kk); acc 16 f32x4.
// Phase 2: om tile -> LDS f32 [64][217], two-pass (kh=0 writes +bias, kh=1 adds).
// Phase 3 (DCN): wave = (nq = px-quarter, kh = K-half of 36 kk); partial accd
//                reduced via padded Rbuf (stride 20, overlays omT after barrier).
// Phase 4: cat GEMM (K=64) N-split across kh; epilogue via T as before.
__global__ __launch_bounds__(512, 4) void k_omdcn(
        const unsigned short* __restrict__ offT, const uint4* __restrict__ fsH4,
        const unsigned short* __restrict__ Wb2, const float* __restrict__ bom,
        const unsigned short* __restrict__ wbd, const float* __restrict__ bd,
        const unsigned short* __restrict__ wbc,
        const float* __restrict__ s_cat, const float* __restrict__ b_cat,
        const float* __restrict__ feat_arm, float* __restrict__ feat) {
    __shared__ float LDSf[16384];                          // 64 KiB
    unsigned short* st = (unsigned short*)LDSf;            // 53,856 B conv input stage
    float* omT = LDSf;                                     // 64*217*4 = 55,552 B (overlay)
    float* Rbuf = LDSf;                                    // 256*20*4 = 20,480 B (overlay, post-P3)
    unsigned short* A3 = (unsigned short*)(LDSf + 13888);  // 64*72*2 = 9,216 B (separate)
    float* T = LDSf;                                       // 64*67*4 (overlay, barriered)
    const uint4* offT4 = (const uint4*)offT;
    const uint4* W4 = (const uint4*)Wb2;
    const int t = threadIdx.x;
    const int b = blockIdx.x >> 6;
    const int h = blockIdx.x & 63;
    // ---- stage conv input rows h-1..h+1, 66 px, zero pad
    for (int i = t; i < 3 * 66 * 16; i += 512) {
        int q = i & 15;
        int rp = i >> 4;
        int r = rp / 66, p = rp - r * 66;
        int gy = h + r - 1, gx = p - 1;
        uint4 v = make_uint4(0, 0, 0, 0);
        if (gy >= 0 && gy < 64 && gx >= 0 && gx < 64)
            v = offT4[((((b << 6) + gy) << 6) + gx) * 16 + q];
        ((uint4*)(st + rp * 136))[q] = v;
    }
    __syncthreads();
    const int lane = t & 63;
    const int w = __builtin_amdgcn_readfirstlane(t >> 6);
    const int nq = w & 3;    // N-quarter (P1/P2), px-quarter (P3/P4)
    const int kh = w >> 2;   // K-half (P1/P3), N-half (P4)
    const int m = lane & 15, ko = lane >> 4;
    // ---- phase 1: conv3x3, K-split (kh picks 18 of 36 kk), barrier-free K-loop
    f32x4 acc[16];
#pragma unroll
    for (int i = 0; i < 16; i++) acc[i] = (f32x4){0.f, 0.f, 0.f, 0.f};
    {
        const int kk0 = kh * 18;
#pragma unroll 4
        for (int kki = 0; kki < 18; kki++) {
            const int kk = kk0 + kki;
            const int tap = kk >> 2, cc = kk & 3;
            const int dy = tap / 3, dx = tap - dy * 3;
            uint4 b4[4];
#pragma unroll
            for (int nt2 = 0; nt2 < 4; nt2++)
                b4[nt2] = W4[(((kk << 4) + (nq << 2) + nt2) << 6) + lane];
            short8 a8[4];
#pragma unroll
            for (int mt = 0; mt < 4; mt++) {
                int p = mt * 16 + m + dx;
                a8[mt] = *(const short8*)(st + (dy * 66 + p) * 136 + (cc << 5) + (ko << 3));
            }
#pragma unroll
            for (int nt2 = 0; nt2 < 4; nt2++)
#pragma unroll
                for (int mt = 0; mt < 4; mt++)
                    acc[nt2 * 4 + mt] = __builtin_amdgcn_mfma_f32_16x16x32_bf16(
                        a8[mt], *(short8*)&b4[nt2], acc[nt2 * 4 + mt], 0, 0, 0);
        }
    }
    __syncthreads();                       // stage reads done -> omT overlay safe
    // ---- phase 2: om tile -> LDS [px][217], two-pass K-reduction
    if (kh == 0) {
#pragma unroll
        for (int nt2 = 0; nt2 < 4; nt2++) {
            int o = ((nq << 2) + nt2) * 16 + m;
            if (o < 216) {
                float bv = bom[o];
#pragma unroll
                for (int mt = 0; mt < 4; mt++) {
                    f32x4 v = acc[nt2 * 4 + mt];
#pragma unroll
                    for (int r = 0; r < 4; r++)
                        omT[(mt * 16 + (ko << 2) + r) * 217 + o] = v[r] + bv;
                }
            }
        }
    }
    __syncthreads();
    if (kh == 1) {
#pragma unroll
        for (int nt2 = 0; nt2 < 4; nt2++) {
            int o = ((nq << 2) + nt2) * 16 + m;
            if (o < 216) {
#pragma unroll
                for (int mt = 0; mt < 4; mt++) {
                    f32x4 v = acc[nt2 * 4 + mt];
#pragma unroll
                    for (int r = 0; r < 4; r++)
                        omT[(mt * 16 + (ko << 2) + r) * 217 + o] += v[r];
                }
            }
        }
    }
    __syncthreads();
    // ---- phase 3: DCN sampling, wave = (px quarter nq, K-half kh), 18 kk each
    const int px = (nq << 4) + m;
    const float fh = (float)h, fw = (float)px;
    const int pb_ = b << 10;
    const float* omrow = omT + px * 217;
    f32x4 accd[4];
#pragma unroll
    for (int nt = 0; nt < 4; nt++) accd[nt] = (f32x4){0.f, 0.f, 0.f, 0.f};
    {
        const int dk0 = kh * 18;
#pragma unroll
        for (int kki = 0; kki < 18; kki++) {
            const int kk = dk0 + kki;
            int k0 = (kk << 5) + (ko << 3);
            int g = k0 / 144;
            int rem = k0 - g * 144;
            int tap = rem >> 4;
            int c0 = rem & 15;
            int ch = g * 9 + tap;
            float oy = omrow[ch];
            float ox = omrow[72 + ch];
            float mmv = omrow[144 + ch];
            mmv = 1.0f / (1.0f + __expf(-mmv));
            float py = fh + (float)(tap / 3 - 1) + oy;
            float pxx = fw + (float)(tap % 3 - 1) + ox;
            float y0f = floorf(py), x0f = floorf(pxx);
            float tyf = py - y0f, txf = pxx - x0f;
            int y0i = (int)y0f, x0i = (int)x0f;
            int y1i = y0i + 1, x1i = x0i + 1;
            bool vy0 = (y0i >= 0) && (y0i < 64);
            bool vy1 = (y1i >= 0) && (y1i < 64);
            bool vx0 = (x0i >= 0) && (x0i < 64);
            bool vx1 = (x1i >= 0) && (x1i < 64);
            float w00 = (vy0 && vx0) ? (1.0f - tyf) * (1.0f - txf) * mmv : 0.0f;
            float w01 = (vy0 && vx1) ? (1.0f - tyf) * txf * mmv : 0.0f;
            float w10 = (vy1 && vx0) ? tyf * (1.0f - txf) * mmv : 0.0f;
            float w11 = (vy1 && vx1) ? tyf * txf * mmv : 0.0f;
            int yc0 = y0i < 0 ? 0 : (y0i > 63 ? 63 : y0i);
            int yc1 = y1i < 0 ? 0 : (y1i > 63 ? 63 : y1i);
            int xc0 = x0i < 0 ? 0 : (x0i > 63 ? 63 : x0i);
            int xc1 = x1i < 0 ? 0 : (x1i > 63 ? 63 : x1i);
            int row0 = (yc0 >> 1) << 5, row1 = (yc1 >> 1) << 5;
            int ci = g * 2 + (c0 >> 3);
            union { uint4 u; h2 h[4]; } C00, C01, C10, C11;
            C00.u = fsH4[((pb_ + row0 + (xc0 >> 1)) << 4) + ci];
            C01.u = fsH4[((pb_ + row0 + (xc1 >> 1)) << 4) + ci];
            C10.u = fsH4[((pb_ + row1 + (xc0 >> 1)) << 4) + ci];
            C11.u = fsH4[((pb_ + row1 + (xc1 >> 1)) << 4) + ci];
            _Float16 h00 = (_Float16)w00, h01 = (_Float16)w01;
            _Float16 h10 = (_Float16)w10, h11 = (_Float16)w11;
            h2 W00 = (h2){h00, h00}, W01 = (h2){h01, h01};
            h2 W10 = (h2){h10, h10}, W11 = (h2){h11, h11};
            union { short8 s; h2 h[4]; } av;
#pragma unroll
            for (int c = 0; c < 4; c++)
                av.h[c] = C00.h[c] * W00 + C01.h[c] * W01 + C10.h[c] * W10 + C11.h[c] * W11;
            const uint4* wb = (const uint4*)wbd + (kk << 2) * 64 + lane;
#pragma unroll
            for (int nt = 0; nt < 4; nt++) {
                uint4 bu = wb[nt * 64];
                accd[nt] = __builtin_amdgcn_mfma_f32_16x16x32_f16(av.s, *(short8*)&bu, accd[nt], 0, 0, 0);
            }
        }
    }
    __syncthreads();                       // omT reads done -> Rbuf overlay safe
    // ---- K-half reduction through Rbuf (stride 20 floats: 16B-aligned, 2-way banks)
    if (kh == 1) {
#pragma unroll
        for (int nt = 0; nt < 4; nt++)
            *(f32x4*)(Rbuf + ((nq << 6) + lane) * 20 + (nt << 2)) = accd[nt];
    }
    __syncthreads();
    if (kh == 0) {
#pragma unroll
        for (int nt = 0; nt < 4; nt++)
            accd[nt] += *(const f32x4*)(Rbuf + ((nq << 6) + lane) * 20 + (nt << 2));
        // ---- phase 4a: align -> A3 bf16 [px][72] (kh=0 waves cover all px)
#pragma unroll
        for (int nt = 0; nt < 4; nt++) {
            int o = (nt << 4) + m;
            float bv = bd[o];
#pragma unroll
            for (int r = 0; r < 4; r++) {
                float v = accd[nt][r] + bv;
                v = v > 0.f ? v : 0.f;
                A3[((nq << 4) + (ko << 2) + r) * 72 + o] = f2bf(v);
            }
        }
    }
    __syncthreads();                       // A3 visible to all waves
    // ---- phase 4b: cat GEMM K=64, N=128; wave = (px quarter nq, N-half kh)
    f32x4 acc2[4];
#pragma unroll
    for (int nt2 = 0; nt2 < 4; nt2++) acc2[nt2] = (f32x4){0.f, 0.f, 0.f, 0.f};
#pragma unroll
    for (int kk2 = 0; kk2 < 2; kk2++) {
        short8 av = *(const short8*)(A3 + ((nq << 4) + m) * 72 + kk2 * 32 + (ko << 3));
#pragma unroll
        for (int nt2 = 0; nt2 < 4; nt2++) {
            uint4 bu = ((const uint4*)wbc)[(kk2 * 8 + (kh << 2) + nt2) * 64 + lane];
            acc2[nt2] = __builtin_amdgcn_mfma_f32_16x16x32_bf16(av, *(short8*)&bu, acc2[nt2], 0, 0, 0);
        }
    }
    // ---- phase 4c: epilogue, two halves through T (overlays omT/Rbuf; barrier first)
#pragma unroll 1
    for (int half = 0; half < 2; half++) {
        __syncthreads();
        if (kh == half) {
#pragma unroll
            for (int nt2 = 0; nt2 < 4; nt2++) {
                int o = (((kh << 2) + nt2) << 4) + m;
                float sc = s_cat[o], bi = b_cat[o];
#pragma unroll
                for (int r = 0; r < 4; r++) {
                    float v = fmaf(acc2[nt2][r], sc, bi);
                    v = v > 0.f ? v : 0.f;
                    T[((nq << 4) + (ko << 2) + r) * 67 + (nt2 << 4) + m] = v;
                }
            }
        }
        __syncthreads();
        for (int i = t; i < 4096; i += 512) {
            int ol = i >> 6, pp = i & 63;
            int gidx = (((b << 7) + half * 64 + ol) << 12) + (h << 6) + pp;
            feat[gidx] = T[pp * 67 + ol] + feat_arm[gidx];
        }
    }
}

extern "C" void kernel_launch(void* const* d_in, const int* in_sizes, int n_in,
                              void* d_out, int out_size, void* d_ws, size_t ws_size,
                              hipStream_t stream) {
    const float* feat_l = (const float*)d_in[0];
    const float* feat_s = (const float*)d_in[1];
    const float* W_fsm  = (const float*)d_in[2];
    const float* s_fsm  = (const float*)d_in[3];
    const float* b_fsm  = (const float*)d_in[4];
    const float* W_off  = (const float*)d_in[5];
    const float* s_off  = (const float*)d_in[6];
    const float* b_off  = (const float*)d_in[7];
    const float* W_om   = (const float*)d_in[8];
    const float* b_om   = (const float*)d_in[9];
    const float* W_dcn  = (const float*)d_in[10];
    const float* b_dcn  = (const float*)d_in[11];
    const float* W_cat  = (const float*)d_in[12];
    const float* s_cat  = (const float*)d_in[13];
    const float* b_cat  = (const float*)d_in[14];

    float* feat     = (float*)d_out;
    float* feat_arm = feat + 4194304;

    float* ws = (float*)d_ws;
    unsigned short* offT = (unsigned short*)ws;                // 2,097,152 f
    uint4* fsT4  = (uint4*)(ws + 9175040);                     //   524,288 f
    unsigned short* wb2   = (unsigned short*)(ws + 9699328);   //  147,456 f
    unsigned short* wbfsm = (unsigned short*)(ws + 9846784);   //    8,192 f
    unsigned short* wboff = (unsigned short*)(ws + 9854976);   //   16,384 f
    unsigned short* wbcat = (unsigned short*)(ws + 9871360);   //    4,096 f
    unsigned short* wbdcn = (unsigned short*)(ws + 9875456);   //   36,864 f
    uint4* fsH4  = (uint4*)(ws + 9912320);                     //   524,288 f

    k_prepfs<<<128, 256, 0, stream>>>(feat_s, fsT4, fsH4);
    k_packall<<<208, 256, 0, stream>>>(W_fsm, W_off, W_cat, W_dcn, W_om,
                                       wbfsm, wboff, wbcat, wbdcn, wb2);

    k12<<<512, 512, 0, stream>>>(feat_l, fsT4, wbfsm, wboff,
                                 s_fsm, b_fsm, s_off, b_off, feat_arm, offT);
    k_omdcn<<<512, 512, 0, stream>>>(offT, fsH4, wb2, b_om, wbdcn, b_dcn,
                                     wbcat, s_cat, b_cat, feat_arm, feat);
}

// Round 2
// 161.661 us; speedup vs baseline: 1.1632x; 1.0900x over previous
//
#include <hip/hip_runtime.h>

// B=8, C=128, H=W=64, G=8, K=9, Cg=16, Cd=64. NCHW, HW=4096.
// MFMA conventions (verified in-problem, round 2):
//   A-frag: lane&15 = m, k-octet = (lane>>4)*8 + j
//   B-frag: lane&15 = n, k-octet = (lane>>4)*8 + j
//   C/D:    col = lane&15 (n), row = (lane>>4)*4 + r (m)
//
// Round-5 changes:
//  * fsH pixel-major gather source replaced by fsC channel-major [b][ci][y2][x2]
//    (16B entry) -> neighbor lanes share 64B L2 lines on DCN gathers.
//  * phase 3 processes kk in PAIRS: all 8 gathers issued before first consume
//    (2-deep pipeline); conv phase 1 prefetches next kk's W-frags.
//  * k_prepfs + k_packall fused into one launch (k_prep).

typedef __attribute__((ext_vector_type(8))) short short8;
typedef __attribute__((ext_vector_type(4))) float f32x4;
typedef _Float16 __attribute__((ext_vector_type(2))) h2;

static __device__ __forceinline__ unsigned short f2bf(float x) {
    union { float f; unsigned int u; } v; v.f = x;
    return (unsigned short)((v.u + 0x7FFF + ((v.u >> 16) & 1)) >> 16);  // RNE
}
static __device__ __forceinline__ unsigned short f2h(float x) {
    union { _Float16 h; unsigned short u; } v; v.h = (_Float16)x;
    return v.u;
}

// ---------------- fused prep: blocks 0..127 = feat_s repack, 128..335 = weight packs
__global__ __launch_bounds__(256) void k_prep(const float* __restrict__ fs,
        uint4* __restrict__ fsT4, uint4* __restrict__ fsC4,
        const float* __restrict__ W_fsm, const float* __restrict__ W_off,
        const float* __restrict__ W_cat, const float* __restrict__ W_dcn,
        const float* __restrict__ W_om,
        unsigned short* __restrict__ wbfsm, unsigned short* __restrict__ wboff,
        unsigned short* __restrict__ wbcat, unsigned short* __restrict__ wbdcn,
        unsigned short* __restrict__ wb2) {
    __shared__ unsigned short st[64 * 136];
    const int t = threadIdx.x;
    if (blockIdx.x < 128) {
        unsigned int* st32 = (unsigned int*)st;
        const int b = blockIdx.x >> 4;
        const int p0 = (blockIdx.x & 15) << 6;
        for (int i = t; i < 64 * 64; i += 256) {
            int c2 = i >> 6, px = i & 63;
            float v0 = fs[(((b << 7) + 2 * c2) << 10) + p0 + px];
            float v1 = fs[(((b << 7) + 2 * c2 + 1) << 10) + p0 + px];
            st32[px * 68 + c2] = (unsigned int)f2bf(v0) | ((unsigned int)f2bf(v1) << 16);
        }
        __syncthreads();
        for (int i = t; i < 64 * 16; i += 256) {
            int px = i >> 4, q = i & 15;
            fsT4[(((b << 10) + p0 + px) << 4) + q] = ((const uint4*)(st + px * 136))[q];
        }
        __syncthreads();
        for (int i = t; i < 64 * 64; i += 256) {
            int c2 = i >> 6, px = i & 63;
            float v0 = fs[(((b << 7) + 2 * c2) << 10) + p0 + px];
            float v1 = fs[(((b << 7) + 2 * c2 + 1) << 10) + p0 + px];
            st32[px * 68 + c2] = (unsigned int)f2h(v0) | ((unsigned int)f2h(v1) << 16);
        }
        __syncthreads();
        // channel-major: fsC4[b][ci][p] , p = global fs pixel index (y2*32+x2)
        for (int i = t; i < 64 * 16; i += 256) {
            int ci = i >> 6, px = i & 63;
            fsC4[(b << 14) + (ci << 10) + p0 + px] = ((const uint4*)(st + px * 136))[ci];
        }
        return;
    }
    int idx = (blockIdx.x - 128) * 256 + t;
    int lane = idx & 63;
    int ml = lane & 15, kl = (lane >> 4) * 8;
    unsigned short tmp[8];
    if (idx < 2048) {                       // wbfsm: K=128, NT=8 (bf16)
        int r = idx >> 6;
        int o = (r % 8) * 16 + ml, k0 = (r / 8) * 32 + kl;
#pragma unroll
        for (int j = 0; j < 8; j++) tmp[j] = f2bf(W_fsm[o * 128 + k0 + j]);
        ((uint4*)wbfsm)[idx] = *(const uint4*)tmp;
    } else if (idx < 6144) {                // wboff: K=256, NT=8, x2 for k>=128 (bf16)
        int i2 = idx - 2048;
        int r = i2 >> 6;
        int o = (r % 8) * 16 + ml, k0 = (r / 8) * 32 + kl;
#pragma unroll
        for (int j = 0; j < 8; j++) {
            int k = k0 + j;
            float f = W_off[o * 256 + k];
            if (k >= 128) f *= 2.0f;
            tmp[j] = f2bf(f);
        }
        ((uint4*)wboff)[i2] = *(const uint4*)tmp;
    } else if (idx < 7168) {                // wbcat: K=64, NT=8 (bf16)
        int i2 = idx - 6144;
        int r = i2 >> 6;
        int o = (r % 8) * 16 + ml, k0 = (r / 8) * 32 + kl;
#pragma unroll
        for (int j = 0; j < 8; j++) tmp[j] = f2bf(W_cat[o * 64 + k0 + j]);
        ((uint4*)wbcat)[i2] = *(const uint4*)tmp;
    } else if (idx < 16384) {               // wbdcn: K=1152 (g,tap,c), NT=4 (f16)
        int i2 = idx - 7168;
        int r = i2 >> 6;
        int o = (r & 3) * 16 + ml, k0 = (r >> 2) * 32 + kl;
#pragma unroll
        for (int j = 0; j < 8; j++) {
            int k = k0 + j;
            int g = k / 144;
            int rem = k - g * 144;
            tmp[j] = f2h(W_dcn[(o * 128 + g * 16 + (rem & 15)) * 9 + (rem >> 4)]);
        }
        ((uint4*)wbdcn)[i2] = *(const uint4*)tmp;
    } else if (idx < 53248) {               // wb2: K=(tap,c), NT=16 (N=256, pad o>=216) bf16
        int i2 = idx - 16384;
        int r = i2 >> 6;
        int nt = r & 15, kk = r >> 4;
        int tap = kk >> 2, cc = kk & 3;
        int o = nt * 16 + ml;
        int c0 = cc * 32 + kl;
#pragma unroll
        for (int j = 0; j < 8; j++) {
            float v = (o < 216) ? W_om[(o * 128 + (c0 + j)) * 9 + tap] : 0.0f;
            tmp[j] = f2bf(v);
        }
        ((uint4*)wb2)[i2] = *(const uint4*)tmp;
    }
}

// ---------------- k12: fused fsm GEMM (K=128) + off GEMM (K=256)
// 512 blocks x 8 waves. wave = (pq = px-quarter, nh = N-half).
__global__ __launch_bounds__(512, 4) void k12(const float* __restrict__ feat_l,
        const uint4* __restrict__ fsT4,
        const unsigned short* __restrict__ wbf, const unsigned short* __restrict__ wbo,
        const float* __restrict__ s_fsm, const float* __restrict__ b_fsm,
        const float* __restrict__ s_off, const float* __restrict__ b_off,
        float* __restrict__ feat_arm, unsigned short* __restrict__ offT) {
    __shared__ unsigned short A1[64 * 136];
    __shared__ unsigned short A2[64 * 264];
    float* E32 = (float*)A1;
    const int t = threadIdx.x;
    const int b = blockIdx.x >> 6;
    const int h = blockIdx.x & 63;
    const int hw0 = h << 6;
    unsigned int* A1w = (unsigned int*)A1;
    for (int i = t; i < 64 * 64; i += 512) {
        int c2 = i >> 6, px = i & 63;
        float v0 = feat_l[(((b << 7) + 2 * c2) << 12) + hw0 + px];
        float v1 = feat_l[(((b << 7) + 2 * c2 + 1) << 12) + hw0 + px];
        A1w[px * 68 + c2] = (unsigned int)f2bf(v0) | ((unsigned int)f2bf(v1) << 16);
    }
    {
        const int h2 = h >> 1;
        int px2 = t >> 4, q = t & 15;
        uint4 v = fsT4[(((b << 10) + (h2 << 5) + px2) << 4) + q];
        ((uint4*)(A2 + (2 * px2) * 264 + 128))[q] = v;
        ((uint4*)(A2 + (2 * px2 + 1) * 264 + 128))[q] = v;
    }
    __syncthreads();
    const int lane = t & 63;
    const int w = __builtin_amdgcn_readfirstlane(t >> 6);
    const int pq = w & 3;    // px quarter
    const int nh = w >> 2;   // N half
    const int m = lane & 15, ko = lane >> 4;
    f32x4 acc[4];
#pragma unroll
    for (int nt2 = 0; nt2 < 4; nt2++) acc[nt2] = (f32x4){0.f, 0.f, 0.f, 0.f};
#pragma unroll
    for (int kk = 0; kk < 4; kk++) {
        short8 av = *(const short8*)(A1 + (pq * 16 + m) * 136 + kk * 32 + ko * 8);
        const uint4* wb = (const uint4*)wbf + (kk * 8 + nh * 4) * 64 + lane;
#pragma unroll
        for (int nt2 = 0; nt2 < 4; nt2++) {
            uint4 bu = wb[nt2 * 64];
            acc[nt2] = __builtin_amdgcn_mfma_f32_16x16x32_bf16(av, *(short8*)&bu, acc[nt2], 0, 0, 0);
        }
    }
#pragma unroll
    for (int nt2 = 0; nt2 < 4; nt2++) {
        int o = ((nh << 2) + nt2) * 16 + m;
        float sc = s_fsm[o], bi = b_fsm[o];
#pragma unroll
        for (int r = 0; r < 4; r++) {
            float v = fmaf(acc[nt2][r], sc, bi);
            v = v > 0.f ? v : 0.f;
            acc[nt2][r] = v;
            A2[(pq * 16 + ko * 4 + r) * 264 + o] = f2bf(v);
        }
    }
#pragma unroll 1
    for (int half = 0; half < 2; half++) {
        __syncthreads();
        if (nh == half) {
#pragma unroll
            for (int nt2 = 0; nt2 < 4; nt2++)
#pragma unroll
                for (int r = 0; r < 4; r++)
                    E32[(pq * 16 + ko * 4 + r) * 67 + nt2 * 16 + m] = acc[nt2][r];
        }
        __syncthreads();
        for (int i = t; i < 4096; i += 512) {
            int ol = i >> 6, pp = i & 63;
            feat_arm[(((b << 7) + half * 64 + ol) << 12) + hw0 + pp] = E32[pp * 67 + ol];
        }
    }
    __syncthreads();
    f32x4 acc2[4];
#pragma unroll
    for (int nt2 = 0; nt2 < 4; nt2++) acc2[nt2] = (f32x4){0.f, 0.f, 0.f, 0.f};
#pragma unroll
    for (int kk = 0; kk < 8; kk++) {
        short8 av = *(const short8*)(A2 + (pq * 16 + m) * 264 + kk * 32 + ko * 8);
        const uint4* wb = (const uint4*)wbo + (kk * 8 + nh * 4) * 64 + lane;
#pragma unroll
        for (int nt2 = 0; nt2 < 4; nt2++) {
            uint4 bu = wb[nt2 * 64];
            acc2[nt2] = __builtin_amdgcn_mfma_f32_16x16x32_bf16(av, *(short8*)&bu, acc2[nt2], 0, 0, 0);
        }
    }
    __syncthreads();
#pragma unroll
    for (int nt2 = 0; nt2 < 4; nt2++) {
        int o = ((nh << 2) + nt2) * 16 + m;
        float sc = s_off[o], bi = b_off[o];
#pragma unroll
        for (int r = 0; r < 4; r++) {
            float v = fmaf(acc2[nt2][r], sc, bi);
            v = v > 0.f ? v : 0.f;
            A2[(pq * 16 + ko * 4 + r) * 264 + o] = f2bf(v);
        }
    }
    __syncthreads();
    for (int i = t; i < 64 * 16; i += 512) {
        int px = i >> 4, q = i & 15;
        ((uint4*)offT)[(((b << 12) + hw0 + px) << 4) + q] = ((const uint4*)(A2 + px * 264))[q];
    }
}

// per-kk DCN gather prep: computes bilinear weights (incl. mask) and issues
// the 4 channel-major gathers. kk is an unroll-time constant in all call sites.
static __device__ __forceinline__ void dcn_prep(int kk, int ko, const float* omrow,
        float fh, float fw, const uint4* __restrict__ fsC4, int b14,
        uint4& c00, uint4& c01, uint4& c10, uint4& c11,
        float& w00, float& w01, float& w10, float& w11) {
    int k0 = (kk << 5) + (ko << 3);
    int g = k0 / 144;
    int rem = k0 - g * 144;
    int tap = rem >> 4;
    int c0 = rem & 15;
    int ch = g * 9 + tap;
    float oy = omrow[ch];
    float ox = omrow[72 + ch];
    float mmv = omrow[144 + ch];
    mmv = 1.0f / (1.0f + __expf(-mmv));
    float py = fh + (float)(tap / 3 - 1) + oy;
    float pxx = fw + (float)(tap % 3 - 1) + ox;
    float y0f = floorf(py), x0f = floorf(pxx);
    float tyf = py - y0f, txf = pxx - x0f;
    int y0i = (int)y0f, x0i = (int)x0f;
    int y1i = y0i + 1, x1i = x0i + 1;
    bool vy0 = (y0i >= 0) && (y0i < 64);
    bool vy1 = (y1i >= 0) && (y1i < 64);
    bool vx0 = (x0i >= 0) && (x0i < 64);
    bool vx1 = (x1i >= 0) && (x1i < 64);
    w00 = (vy0 && vx0) ? (1.0f - tyf) * (1.0f - txf) * mmv : 0.0f;
    w01 = (vy0 && vx1) ? (1.0f - tyf) * txf * mmv : 0.0f;
    w10 = (vy1 && vx0) ? tyf * (1.0f - txf) * mmv : 0.0f;
    w11 = (vy1 && vx1) ? tyf * txf * mmv : 0.0f;
    int yc0 = y0i < 0 ? 0 : (y0i > 63 ? 63 : y0i);
    int yc1 = y1i < 0 ? 0 : (y1i > 63 ? 63 : y1i);
    int xc0 = x0i < 0 ? 0 : (x0i > 63 ? 63 : x0i);
    int xc1 = x1i < 0 ? 0 : (x1i > 63 ? 63 : x1i);
    int row0 = (yc0 >> 1) << 5, row1 = (yc1 >> 1) << 5;
    int ci = g * 2 + (c0 >> 3);
    const uint4* base = fsC4 + b14 + (ci << 10);
    c00 = base[row0 + (xc0 >> 1)];
    c01 = base[row0 + (xc1 >> 1)];
    c10 = base[row1 + (xc0 >> 1)];
    c11 = base[row1 + (xc1 >> 1)];
}

static __device__ __forceinline__ void dcn_consume(int kk,
        const uint4& c00, const uint4& c01, const uint4& c10, const uint4& c11,
        float w00, float w01, float w10, float w11,
        const uint4* __restrict__ wbd4, int lane, f32x4* accd) {
    _Float16 h00 = (_Float16)w00, h01 = (_Float16)w01;
    _Float16 h10 = (_Float16)w10, h11 = (_Float16)w11;
    h2 W00 = (h2){h00, h00}, W01 = (h2){h01, h01};
    h2 W10 = (h2){h10, h10}, W11 = (h2){h11, h11};
    union { uint4 u; h2 h[4]; } U00, U01, U10, U11;
    U00.u = c00; U01.u = c01; U10.u = c10; U11.u = c11;
    union { short8 s; h2 h[4]; } av;
#pragma unroll
    for (int c = 0; c < 4; c++)
        av.h[c] = U00.h[c] * W00 + U01.h[c] * W01 + U10.h[c] * W10 + U11.h[c] * W11;
    const uint4* wb = wbd4 + (kk << 2) * 64 + lane;
#pragma unroll
    for (int nt = 0; nt < 4; nt++) {
        uint4 bu = wb[nt * 64];
        accd[nt] = __builtin_amdgcn_mfma_f32_16x16x32_f16(av.s, *(short8*)&bu, accd[nt], 0, 0, 0);
    }
}

// ---------------- k_omdcn: FUSED conv3x3(om) -> LDS -> DCNv2 sample -> cat GEMM -> feat
// 512 blocks (b, row h) x 8 waves (512 threads).
__global__ __launch_bounds__(512, 4) void k_omdcn(
        const unsigned short* __restrict__ offT, const uint4* __restrict__ fsC4,
        const unsigned short* __restrict__ Wb2, const float* __restrict__ bom,
        const unsigned short* __restrict__ wbd, const float* __restrict__ bd,
        const unsigned short* __restrict__ wbc,
        const float* __restrict__ s_cat, const float* __restrict__ b_cat,
        const float* __restrict__ feat_arm, float* __restrict__ feat) {
    __shared__ float LDSf[16384];                          // 64 KiB
    unsigned short* st = (unsigned short*)LDSf;            // 53,856 B conv input stage
    float* omT = LDSf;                                     // 64*217*4 = 55,552 B (overlay)
    float* Rbuf = LDSf;                                    // overlay, post-P3
    unsigned short* A3 = (unsigned short*)(LDSf + 13888);  // 64*72*2 = 9,216 B (separate)
    float* T = LDSf;                                       // 64*67*4 (overlay, barriered)
    const uint4* offT4 = (const uint4*)offT;
    const uint4* W4 = (const uint4*)Wb2;
    const uint4* wbd4 = (const uint4*)wbd;
    const int t = threadIdx.x;
    const int b = blockIdx.x >> 6;
    const int h = blockIdx.x & 63;
    // ---- stage conv input rows h-1..h+1, 66 px, zero pad
    for (int i = t; i < 3 * 66 * 16; i += 512) {
        int q = i & 15;
        int rp = i >> 4;
        int r = rp / 66, p = rp - r * 66;
        int gy = h + r - 1, gx = p - 1;
        uint4 v = make_uint4(0, 0, 0, 0);
        if (gy >= 0 && gy < 64 && gx >= 0 && gx < 64)
            v = offT4[((((b << 6) + gy) << 6) + gx) * 16 + q];
        ((uint4*)(st + rp * 136))[q] = v;
    }
    __syncthreads();
    const int lane = t & 63;
    const int w = __builtin_amdgcn_readfirstlane(t >> 6);
    const int nq = w & 3;    // N-quarter (P1/P2), px-quarter (P3/P4)
    const int kh = w >> 2;   // K-half (P1/P3), N-half (P4)
    const int m = lane & 15, ko = lane >> 4;
    // ---- phase 1: conv3x3, K-split (kh picks 18 of 36 kk), W-frag prefetch 1-deep
    f32x4 acc[16];
#pragma unroll
    for (int i = 0; i < 16; i++) acc[i] = (f32x4){0.f, 0.f, 0.f, 0.f};
    {
        const int kk0 = kh * 18;
        uint4 b4[4];
#pragma unroll
        for (int nt2 = 0; nt2 < 4; nt2++)
            b4[nt2] = W4[(((kk0 << 4) + (nq << 2) + nt2) << 6) + lane];
#pragma unroll
        for (int kki = 0; kki < 18; kki++) {
            const int kk = kk0 + kki;
            const int tap = kk >> 2, cc = kk & 3;
            const int dy = tap / 3, dx = tap - dy * 3;
            uint4 b4n[4];
            if (kki < 17) {
#pragma unroll
                for (int nt2 = 0; nt2 < 4; nt2++)
                    b4n[nt2] = W4[((((kk + 1) << 4) + (nq << 2) + nt2) << 6) + lane];
            }
            short8 a8[4];
#pragma unroll
            for (int mt = 0; mt < 4; mt++) {
                int p = mt * 16 + m + dx;
                a8[mt] = *(const short8*)(st + (dy * 66 + p) * 136 + (cc << 5) + (ko << 3));
            }
#pragma unroll
            for (int nt2 = 0; nt2 < 4; nt2++)
#pragma unroll
                for (int mt = 0; mt < 4; mt++)
                    acc[nt2 * 4 + mt] = __builtin_amdgcn_mfma_f32_16x16x32_bf16(
                        a8[mt], *(short8*)&b4[nt2], acc[nt2 * 4 + mt], 0, 0, 0);
            if (kki < 17) {
#pragma unroll
                for (int nt2 = 0; nt2 < 4; nt2++) b4[nt2] = b4n[nt2];
            }
        }
    }
    __syncthreads();                       // stage reads done -> omT overlay safe
    // ---- phase 2: om tile -> LDS [px][217], two-pass K-reduction
    if (kh == 0) {
#pragma unroll
        for (int nt2 = 0; nt2 < 4; nt2++) {
            int o = ((nq << 2) + nt2) * 16 + m;
            if (o < 216) {
                float bv = bom[o];
#pragma unroll
                for (int mt = 0; mt < 4; mt++) {
                    f32x4 v = acc[nt2 * 4 + mt];
#pragma unroll
                    for (int r = 0; r < 4; r++)
                        omT[(mt * 16 + (ko << 2) + r) * 217 + o] = v[r] + bv;
                }
            }
        }
    }
    __syncthreads();
    if (kh == 1) {
#pragma unroll
        for (int nt2 = 0; nt2 < 4; nt2++) {
            int o = ((nq << 2) + nt2) * 16 + m;
            if (o < 216) {
#pragma unroll
                for (int mt = 0; mt < 4; mt++) {
                    f32x4 v = acc[nt2 * 4 + mt];
#pragma unroll
                    for (int r = 0; r < 4; r++)
                        omT[(mt * 16 + (ko << 2) + r) * 217 + o] += v[r];
                }
            }
        }
    }
    __syncthreads();
    // ---- phase 3: DCN sampling, wave = (px quarter nq, K-half kh), 18 kk in 9 pairs
    const int px = (nq << 4) + m;
    const float fh = (float)h, fw = (float)px;
    const int b14 = b << 14;
    const float* omrow = omT + px * 217;
    f32x4 accd[4];
#pragma unroll
    for (int nt = 0; nt < 4; nt++) accd[nt] = (f32x4){0.f, 0.f, 0.f, 0.f};
    {
        const int dk0 = kh * 18;
#pragma unroll
        for (int kp = 0; kp < 9; kp++) {
            const int kkA = dk0 + 2 * kp;
            const int kkB = kkA + 1;
            uint4 a00, a01, a10, a11, e00, e01, e10, e11;
            float wa00, wa01, wa10, wa11, wb00, wb01, wb10, wb11;
            dcn_prep(kkA, ko, omrow, fh, fw, fsC4, b14,
                     a00, a01, a10, a11, wa00, wa01, wa10, wa11);
            dcn_prep(kkB, ko, omrow, fh, fw, fsC4, b14,
                     e00, e01, e10, e11, wb00, wb01, wb10, wb11);
            dcn_consume(kkA, a00, a01, a10, a11, wa00, wa01, wa10, wa11, wbd4, lane, accd);
            dcn_consume(kkB, e00, e01, e10, e11, wb00, wb01, wb10, wb11, wbd4, lane, accd);
        }
    }
    __syncthreads();                       // omT reads done -> Rbuf overlay safe
    // ---- K-half reduction through Rbuf (stride 20 floats)
    if (kh == 1) {
#pragma unroll
        for (int nt = 0; nt < 4; nt++)
            *(f32x4*)(Rbuf + ((nq << 6) + lane) * 20 + (nt << 2)) = accd[nt];
    }
    __syncthreads();
    if (kh == 0) {
#pragma unroll
        for (int nt = 0; nt < 4; nt++)
            accd[nt] += *(const f32x4*)(Rbuf + ((nq << 6) + lane) * 20 + (nt << 2));
        // ---- phase 4a: align -> A3 bf16 [px][72]
#pragma unroll
        for (int nt = 0; nt < 4; nt++) {
            int o = (nt << 4) + m;
            float bv = bd[o];
#pragma unroll
            for (int r = 0; r < 4; r++) {
                float v = accd[nt][r] + bv;
                v = v > 0.f ? v : 0.f;
                A3[((nq << 4) + (ko << 2) + r) * 72 + o] = f2bf(v);
            }
        }
    }
    __syncthreads();                       // A3 visible to all waves
    // ---- phase 4b: cat GEMM K=64, N=128; wave = (px quarter nq, N-half kh)
    f32x4 acc2[4];
#pragma unroll
    for (int nt2 = 0; nt2 < 4; nt2++) acc2[nt2] = (f32x4){0.f, 0.f, 0.f, 0.f};
#pragma unroll
    for (int kk2 = 0; kk2 < 2; kk2++) {
        short8 av = *(const short8*)(A3 + ((nq << 4) + m) * 72 + kk2 * 32 + (ko << 3));
#pragma unroll
        for (int nt2 = 0; nt2 < 4; nt2++) {
            uint4 bu = ((const uint4*)wbc)[(kk2 * 8 + (kh << 2) + nt2) * 64 + lane];
            acc2[nt2] = __builtin_amdgcn_mfma_f32_16x16x32_bf16(av, *(short8*)&bu, acc2[nt2], 0, 0, 0);
        }
    }
    // ---- phase 4c: epilogue, two halves through T (overlays omT/Rbuf; barrier first)
#pragma unroll 1
    for (int half = 0; half < 2; half++) {
        __syncthreads();
        if (kh == half) {
#pragma unroll
            for (int nt2 = 0; nt2 < 4; nt2++) {
                int o = (((kh << 2) + nt2) << 4) + m;
                float sc = s_cat[o], bi = b_cat[o];
#pragma unroll
                for (int r = 0; r < 4; r++) {
                    float v = fmaf(acc2[nt2][r], sc, bi);
                    v = v > 0.f ? v : 0.f;
                    T[((nq << 4) + (ko << 2) + r) * 67 + (nt2 << 4) + m] = v;
                }
            }
        }
        __syncthreads();
        for (int i = t; i < 4096; i += 512) {
            int ol = i >> 6, pp = i & 63;
            int gidx = (((b << 7) + half * 64 + ol) << 12) + (h << 6) + pp;
            feat[gidx] = T[pp * 67 + ol] + feat_arm[gidx];
        }
    }
}

extern "C" void kernel_launch(void* const* d_in, const int* in_sizes, int n_in,
                              void* d_out, int out_size, void* d_ws, size_t ws_size,
                              hipStream_t stream) {
    const float* feat_l = (const float*)d_in[0];
    const float* feat_s = (const float*)d_in[1];
    const float* W_fsm  = (const float*)d_in[2];
    const float* s_fsm  = (const float*)d_in[3];
    const float* b_fsm  = (const float*)d_in[4];
    const float* W_off  = (const float*)d_in[5];
    const float* s_off  = (const float*)d_in[6];
    const float* b_off  = (const float*)d_in[7];
    const float* W_om   = (const float*)d_in[8];
    const float* b_om   = (const float*)d_in[9];
    const float* W_dcn  = (const float*)d_in[10];
    const float* b_dcn  = (const float*)d_in[11];
    const float* W_cat  = (const float*)d_in[12];
    const float* s_cat  = (const float*)d_in[13];
    const float* b_cat  = (const float*)d_in[14];

    float* feat     = (float*)d_out;
    float* feat_arm = feat + 4194304;

    float* ws = (float*)d_ws;
    unsigned short* offT = (unsigned short*)ws;                // 2,097,152 f
    uint4* fsT4  = (uint4*)(ws + 9175040);                     //   524,288 f
    unsigned short* wb2   = (unsigned short*)(ws + 9699328);   //  147,456 f
    unsigned short* wbfsm = (unsigned short*)(ws + 9846784);   //    8,192 f
    unsigned short* wboff = (unsigned short*)(ws + 9854976);   //   16,384 f
    unsigned short* wbcat = (unsigned short*)(ws + 9871360);   //    4,096 f
    unsigned short* wbdcn = (unsigned short*)(ws + 9875456);   //   36,864 f
    uint4* fsC4  = (uint4*)(ws + 9912320);                     //   524,288 f

    k_prep<<<336, 256, 0, stream>>>(feat_s, fsT4, fsC4, W_fsm, W_off, W_cat,
                                    W_dcn, W_om, wbfsm, wboff, wbcat, wbdcn, wb2);

    k12<<<512, 512, 0, stream>>>(feat_l, fsT4, wbfsm, wboff,
                                 s_fsm, b_fsm, s_off, b_off, feat_arm, offT);
    k_omdcn<<<512, 512, 0, stream>>>(offT, fsC4, wb2, b_om, wbdcn, b_dcn,
                                     wbcat, s_cat, b_cat, feat_arm, feat);
}

// Round 3
// 161.285 us; speedup vs baseline: 1.1659x; 1.0023x over previous
//
#include <hip/hip_runtime.h>

// B=8, C=128, H=W=64, G=8, K=9, Cg=16, Cd=64. NCHW, HW=4096.
// MFMA conventions (verified in-problem, round 2):
//   A-frag: lane&15 = m, k-octet = (lane>>4)*8 + j
//   B-frag: lane&15 = n, k-octet = (lane>>4)*8 + j
//   C/D:    col = lane&15 (n), row = (lane>>4)*4 + r (m)
//
// Round-6 changes:
//  * k_omdcn phase 1: N-split-8 (wave owns 2 N-tiles, all 36 kk) -> NO K-reduction,
//    single-pass omT write (removes one full pass + 1 barrier).
//  * Direct float4 epilogue stores (feat_arm in k12, feat in k_omdcn): each lane
//    owns 4 consecutive px for one channel -> removes LDS transpose + 4 barriers each.
//  * Phase 3: rolling 3-deep gather pipeline (was pairwise 2-deep blocked).
//  * k12: __launch_bounds__(512,6) -> 3 blocks/CU (LDS 51.2 KB).

typedef __attribute__((ext_vector_type(8))) short short8;
typedef __attribute__((ext_vector_type(4))) float f32x4;
typedef _Float16 __attribute__((ext_vector_type(2))) h2;

static __device__ __forceinline__ unsigned short f2bf(float x) {
    union { float f; unsigned int u; } v; v.f = x;
    return (unsigned short)((v.u + 0x7FFF + ((v.u >> 16) & 1)) >> 16);  // RNE
}
static __device__ __forceinline__ unsigned short f2h(float x) {
    union { _Float16 h; unsigned short u; } v; v.h = (_Float16)x;
    return v.u;
}

// ---------------- fused prep: blocks 0..127 = feat_s repack, 128..335 = weight packs
__global__ __launch_bounds__(256) void k_prep(const float* __restrict__ fs,
        uint4* __restrict__ fsT4, uint4* __restrict__ fsC4,
        const float* __restrict__ W_fsm, const float* __restrict__ W_off,
        const float* __restrict__ W_cat, const float* __restrict__ W_dcn,
        const float* __restrict__ W_om,
        unsigned short* __restrict__ wbfsm, unsigned short* __restrict__ wboff,
        unsigned short* __restrict__ wbcat, unsigned short* __restrict__ wbdcn,
        unsigned short* __restrict__ wb2) {
    __shared__ unsigned short st[64 * 136];
    const int t = threadIdx.x;
    if (blockIdx.x < 128) {
        unsigned int* st32 = (unsigned int*)st;
        const int b = blockIdx.x >> 4;
        const int p0 = (blockIdx.x & 15) << 6;
        for (int i = t; i < 64 * 64; i += 256) {
            int c2 = i >> 6, px = i & 63;
            float v0 = fs[(((b << 7) + 2 * c2) << 10) + p0 + px];
            float v1 = fs[(((b << 7) + 2 * c2 + 1) << 10) + p0 + px];
            st32[px * 68 + c2] = (unsigned int)f2bf(v0) | ((unsigned int)f2bf(v1) << 16);
        }
        __syncthreads();
        for (int i = t; i < 64 * 16; i += 256) {
            int px = i >> 4, q = i & 15;
            fsT4[(((b << 10) + p0 + px) << 4) + q] = ((const uint4*)(st + px * 136))[q];
        }
        __syncthreads();
        for (int i = t; i < 64 * 64; i += 256) {
            int c2 = i >> 6, px = i & 63;
            float v0 = fs[(((b << 7) + 2 * c2) << 10) + p0 + px];
            float v1 = fs[(((b << 7) + 2 * c2 + 1) << 10) + p0 + px];
            st32[px * 68 + c2] = (unsigned int)f2h(v0) | ((unsigned int)f2h(v1) << 16);
        }
        __syncthreads();
        // channel-major: fsC4[b][ci][p] , p = global fs pixel index (y2*32+x2)
        for (int i = t; i < 64 * 16; i += 256) {
            int ci = i >> 6, px = i & 63;
            fsC4[(b << 14) + (ci << 10) + p0 + px] = ((const uint4*)(st + px * 136))[ci];
        }
        return;
    }
    int idx = (blockIdx.x - 128) * 256 + t;
    int lane = idx & 63;
    int ml = lane & 15, kl = (lane >> 4) * 8;
    unsigned short tmp[8];
    if (idx < 2048) {                       // wbfsm: K=128, NT=8 (bf16)
        int r = idx >> 6;
        int o = (r % 8) * 16 + ml, k0 = (r / 8) * 32 + kl;
#pragma unroll
        for (int j = 0; j < 8; j++) tmp[j] = f2bf(W_fsm[o * 128 + k0 + j]);
        ((uint4*)wbfsm)[idx] = *(const uint4*)tmp;
    } else if (idx < 6144) {                // wboff: K=256, NT=8, x2 for k>=128 (bf16)
        int i2 = idx - 2048;
        int r = i2 >> 6;
        int o = (r % 8) * 16 + ml, k0 = (r / 8) * 32 + kl;
#pragma unroll
        for (int j = 0; j < 8; j++) {
            int k = k0 + j;
            float f = W_off[o * 256 + k];
            if (k >= 128) f *= 2.0f;
            tmp[j] = f2bf(f);
        }
        ((uint4*)wboff)[i2] = *(const uint4*)tmp;
    } else if (idx < 7168) {                // wbcat: K=64, NT=8 (bf16)
        int i2 = idx - 6144;
        int r = i2 >> 6;
        int o = (r % 8) * 16 + ml, k0 = (r / 8) * 32 + kl;
#pragma unroll
        for (int j = 0; j < 8; j++) tmp[j] = f2bf(W_cat[o * 64 + k0 + j]);
        ((uint4*)wbcat)[i2] = *(const uint4*)tmp;
    } else if (idx < 16384) {               // wbdcn: K=1152 (g,tap,c), NT=4 (f16)
        int i2 = idx - 7168;
        int r = i2 >> 6;
        int o = (r & 3) * 16 + ml, k0 = (r >> 2) * 32 + kl;
#pragma unroll
        for (int j = 0; j < 8; j++) {
            int k = k0 + j;
            int g = k / 144;
            int rem = k - g * 144;
            tmp[j] = f2h(W_dcn[(o * 128 + g * 16 + (rem & 15)) * 9 + (rem >> 4)]);
        }
        ((uint4*)wbdcn)[i2] = *(const uint4*)tmp;
    } else if (idx < 53248) {               // wb2: K=(tap,c), NT=16 (N=256, pad o>=216) bf16
        int i2 = idx - 16384;
        int r = i2 >> 6;
        int nt = r & 15, kk = r >> 4;
        int tap = kk >> 2, cc = kk & 3;
        int o = nt * 16 + ml;
        int c0 = cc * 32 + kl;
#pragma unroll
        for (int j = 0; j < 8; j++) {
            float v = (o < 216) ? W_om[(o * 128 + (c0 + j)) * 9 + tap] : 0.0f;
            tmp[j] = f2bf(v);
        }
        ((uint4*)wb2)[i2] = *(const uint4*)tmp;
    }
}

// ---------------- k12: fused fsm GEMM (K=128) + off GEMM (K=256)
// 512 blocks x 8 waves. wave = (pq = px-quarter, nh = N-half).
// Direct float4 feat_arm stores (no E32 round-trip). 3 blocks/CU target.
__global__ __launch_bounds__(512, 6) void k12(const float* __restrict__ feat_l,
        const uint4* __restrict__ fsT4,
        const unsigned short* __restrict__ wbf, const unsigned short* __restrict__ wbo,
        const float* __restrict__ s_fsm, const float* __restrict__ b_fsm,
        const float* __restrict__ s_off, const float* __restrict__ b_off,
        float* __restrict__ feat_arm, unsigned short* __restrict__ offT) {
    __shared__ unsigned short A1[64 * 136];
    __shared__ unsigned short A2[64 * 264];
    const int t = threadIdx.x;
    const int b = blockIdx.x >> 6;
    const int h = blockIdx.x & 63;
    const int hw0 = h << 6;
    unsigned int* A1w = (unsigned int*)A1;
    for (int i = t; i < 64 * 64; i += 512) {
        int c2 = i >> 6, px = i & 63;
        float v0 = feat_l[(((b << 7) + 2 * c2) << 12) + hw0 + px];
        float v1 = feat_l[(((b << 7) + 2 * c2 + 1) << 12) + hw0 + px];
        A1w[px * 68 + c2] = (unsigned int)f2bf(v0) | ((unsigned int)f2bf(v1) << 16);
    }
    {
        const int h2 = h >> 1;
        int px2 = t >> 4, q = t & 15;
        uint4 v = fsT4[(((b << 10) + (h2 << 5) + px2) << 4) + q];
        ((uint4*)(A2 + (2 * px2) * 264 + 128))[q] = v;
        ((uint4*)(A2 + (2 * px2 + 1) * 264 + 128))[q] = v;
    }
    __syncthreads();
    const int lane = t & 63;
    const int w = __builtin_amdgcn_readfirstlane(t >> 6);
    const int pq = w & 3;    // px quarter
    const int nh = w >> 2;   // N half
    const int m = lane & 15, ko = lane >> 4;
    f32x4 acc[4];
#pragma unroll
    for (int nt2 = 0; nt2 < 4; nt2++) acc[nt2] = (f32x4){0.f, 0.f, 0.f, 0.f};
#pragma unroll
    for (int kk = 0; kk < 4; kk++) {
        short8 av = *(const short8*)(A1 + (pq * 16 + m) * 136 + kk * 32 + ko * 8);
        const uint4* wb = (const uint4*)wbf + (kk * 8 + nh * 4) * 64 + lane;
#pragma unroll
        for (int nt2 = 0; nt2 < 4; nt2++) {
            uint4 bu = wb[nt2 * 64];
            acc[nt2] = __builtin_amdgcn_mfma_f32_16x16x32_bf16(av, *(short8*)&bu, acc[nt2], 0, 0, 0);
        }
    }
    // fsm epilogue: bf16 -> A2 (off GEMM input) + direct float4 feat_arm store
    {
        const int px0 = pq * 16 + (ko << 2);
#pragma unroll
        for (int nt2 = 0; nt2 < 4; nt2++) {
            int o = ((nh << 2) + nt2) * 16 + m;
            float sc = s_fsm[o], bi = b_fsm[o];
            f32x4 v;
#pragma unroll
            for (int r = 0; r < 4; r++) {
                float vv = fmaf(acc[nt2][r], sc, bi);
                vv = vv > 0.f ? vv : 0.f;
                v[r] = vv;
                A2[(px0 + r) * 264 + o] = f2bf(vv);
            }
            *(f32x4*)(feat_arm + ((((b << 7) + o) << 12) + hw0 + px0)) = v;
        }
    }
    __syncthreads();
    f32x4 acc2[4];
#pragma unroll
    for (int nt2 = 0; nt2 < 4; nt2++) acc2[nt2] = (f32x4){0.f, 0.f, 0.f, 0.f};
#pragma unroll
    for (int kk = 0; kk < 8; kk++) {
        short8 av = *(const short8*)(A2 + (pq * 16 + m) * 264 + kk * 32 + ko * 8);
        const uint4* wb = (const uint4*)wbo + (kk * 8 + nh * 4) * 64 + lane;
#pragma unroll
        for (int nt2 = 0; nt2 < 4; nt2++) {
            uint4 bu = wb[nt2 * 64];
            acc2[nt2] = __builtin_amdgcn_mfma_f32_16x16x32_bf16(av, *(short8*)&bu, acc2[nt2], 0, 0, 0);
        }
    }
    __syncthreads();
#pragma unroll
    for (int nt2 = 0; nt2 < 4; nt2++) {
        int o = ((nh << 2) + nt2) * 16 + m;
        float sc = s_off[o], bi = b_off[o];
#pragma unroll
        for (int r = 0; r < 4; r++) {
            float v = fmaf(acc2[nt2][r], sc, bi);
            v = v > 0.f ? v : 0.f;
            A2[(pq * 16 + ko * 4 + r) * 264 + o] = f2bf(v);
        }
    }
    __syncthreads();
    for (int i = t; i < 64 * 16; i += 512) {
        int px = i >> 4, q = i & 15;
        ((uint4*)offT)[(((b << 12) + hw0 + px) << 4) + q] = ((const uint4*)(A2 + px * 264))[q];
    }
}

// per-kk DCN gather prep: computes bilinear weights (incl. mask) and issues
// the 4 channel-major gathers. kk is an unroll-time constant in all call sites.
static __device__ __forceinline__ void dcn_prep(int kk, int ko, const float* omrow,
        float fh, float fw, const uint4* __restrict__ fsC4, int b14,
        uint4& c00, uint4& c01, uint4& c10, uint4& c11,
        float& w00, float& w01, float& w10, float& w11) {
    int k0 = (kk << 5) + (ko << 3);
    int g = k0 / 144;
    int rem = k0 - g * 144;
    int tap = rem >> 4;
    int c0 = rem & 15;
    int ch = g * 9 + tap;
    float oy = omrow[ch];
    float ox = omrow[72 + ch];
    float mmv = omrow[144 + ch];
    mmv = 1.0f / (1.0f + __expf(-mmv));
    float py = fh + (float)(tap / 3 - 1) + oy;
    float pxx = fw + (float)(tap % 3 - 1) + ox;
    float y0f = floorf(py), x0f = floorf(pxx);
    float tyf = py - y0f, txf = pxx - x0f;
    int y0i = (int)y0f, x0i = (int)x0f;
    int y1i = y0i + 1, x1i = x0i + 1;
    bool vy0 = (y0i >= 0) && (y0i < 64);
    bool vy1 = (y1i >= 0) && (y1i < 64);
    bool vx0 = (x0i >= 0) && (x0i < 64);
    bool vx1 = (x1i >= 0) && (x1i < 64);
    w00 = (vy0 && vx0) ? (1.0f - tyf) * (1.0f - txf) * mmv : 0.0f;
    w01 = (vy0 && vx1) ? (1.0f - tyf) * txf * mmv : 0.0f;
    w10 = (vy1 && vx0) ? tyf * (1.0f - txf) * mmv : 0.0f;
    w11 = (vy1 && vx1) ? tyf * txf * mmv : 0.0f;
    int yc0 = y0i < 0 ? 0 : (y0i > 63 ? 63 : y0i);
    int yc1 = y1i < 0 ? 0 : (y1i > 63 ? 63 : y1i);
    int xc0 = x0i < 0 ? 0 : (x0i > 63 ? 63 : x0i);
    int xc1 = x1i < 0 ? 0 : (x1i > 63 ? 63 : x1i);
    int row0 = (yc0 >> 1) << 5, row1 = (yc1 >> 1) << 5;
    int ci = g * 2 + (c0 >> 3);
    const uint4* base = fsC4 + b14 + (ci << 10);
    c00 = base[row0 + (xc0 >> 1)];
    c01 = base[row0 + (xc1 >> 1)];
    c10 = base[row1 + (xc0 >> 1)];
    c11 = base[row1 + (xc1 >> 1)];
}

static __device__ __forceinline__ void dcn_consume(int kk,
        const uint4& c00, const uint4& c01, const uint4& c10, const uint4& c11,
        float w00, float w01, float w10, float w11,
        const uint4* __restrict__ wbd4, int lane, f32x4* accd) {
    _Float16 h00 = (_Float16)w00, h01 = (_Float16)w01;
    _Float16 h10 = (_Float16)w10, h11 = (_Float16)w11;
    h2 W00 = (h2){h00, h00}, W01 = (h2){h01, h01};
    h2 W10 = (h2){h10, h10}, W11 = (h2){h11, h11};
    union { uint4 u; h2 h[4]; } U00, U01, U10, U11;
    U00.u = c00; U01.u = c01; U10.u = c10; U11.u = c11;
    union { short8 s; h2 h[4]; } av;
#pragma unroll
    for (int c = 0; c < 4; c++)
        av.h[c] = U00.h[c] * W00 + U01.h[c] * W01 + U10.h[c] * W10 + U11.h[c] * W11;
    const uint4* wb = wbd4 + (kk << 2) * 64 + lane;
    __builtin_amdgcn_s_setprio(1);
#pragma unroll
    for (int nt = 0; nt < 4; nt++) {
        uint4 bu = wb[nt * 64];
        accd[nt] = __builtin_amdgcn_mfma_f32_16x16x32_f16(av.s, *(short8*)&bu, accd[nt], 0, 0, 0);
    }
    __builtin_amdgcn_s_setprio(0);
}

// ---------------- k_omdcn: FUSED conv3x3(om) -> LDS -> DCNv2 sample -> cat GEMM -> feat
// 512 blocks (b, row h) x 8 waves (512 threads).
// Phase 1 (conv): N-split-8 (wave owns NT pair {2w, 2w+1}, all 36 kk) - no reduction.
// Phase 2: single-pass omT write (+bias).
// Phase 3 (DCN): wave = (px-quarter nq, K-half kh); rolling 3-deep gather pipeline;
//                partials reduced via Rbuf (stride 20, overlays omT after barrier).
// Phase 4: cat GEMM (K=64) N-split across kh; DIRECT float4 epilogue stores.
__global__ __launch_bounds__(512, 4) void k_omdcn(
        const unsigned short* __restrict__ offT, const uint4* __restrict__ fsC4,
        const unsigned short* __restrict__ Wb2, const float* __restrict__ bom,
        const unsigned short* __restrict__ wbd, const float* __restrict__ bd,
        const unsigned short* __restrict__ wbc,
        const float* __restrict__ s_cat, const float* __restrict__ b_cat,
        const float* __restrict__ feat_arm, float* __restrict__ feat) {
    __shared__ float LDSf[16384];                          // 64 KiB
    unsigned short* st = (unsigned short*)LDSf;            // 53,856 B conv input stage
    float* omT = LDSf;                                     // 64*217*4 = 55,552 B (overlay)
    float* Rbuf = LDSf;                                    // overlay, post-P3 (20.5 KB)
    unsigned short* A3 = (unsigned short*)(LDSf + 13888);  // 64*72*2 = 9,216 B (separate)
    const uint4* offT4 = (const uint4*)offT;
    const uint4* W4 = (const uint4*)Wb2;
    const uint4* wbd4 = (const uint4*)wbd;
    const int t = threadIdx.x;
    const int b = blockIdx.x >> 6;
    const int h = blockIdx.x & 63;
    // ---- stage conv input rows h-1..h+1, 66 px, zero pad
    for (int i = t; i < 3 * 66 * 16; i += 512) {
        int q = i & 15;
        int rp = i >> 4;
        int r = rp / 66, p = rp - r * 66;
        int gy = h + r - 1, gx = p - 1;
        uint4 v = make_uint4(0, 0, 0, 0);
        if (gy >= 0 && gy < 64 && gx >= 0 && gx < 64)
            v = offT4[((((b << 6) + gy) << 6) + gx) * 16 + q];
        ((uint4*)(st + rp * 136))[q] = v;
    }
    __syncthreads();
    const int lane = t & 63;
    const int w = __builtin_amdgcn_readfirstlane(t >> 6);
    const int m = lane & 15, ko = lane >> 4;
    // ---- phase 1: conv3x3, N-split-8: wave w owns NT {2w, 2w+1}, full K (36 kk)
    f32x4 acc[2][4];   // [nt2][mt]
#pragma unroll
    for (int i = 0; i < 2; i++)
#pragma unroll
        for (int j = 0; j < 4; j++) acc[i][j] = (f32x4){0.f, 0.f, 0.f, 0.f};
    {
        const int ntb = w << 1;
        uint4 b4c[2];
#pragma unroll
        for (int nt2 = 0; nt2 < 2; nt2++)
            b4c[nt2] = W4[((ntb + nt2) << 6) + lane];
#pragma unroll
        for (int kk = 0; kk < 36; kk++) {
            const int tap = kk >> 2, cc = kk & 3;
            const int dy = tap / 3, dx = tap - dy * 3;
            uint4 b4n[2];
            if (kk < 35) {
#pragma unroll
                for (int nt2 = 0; nt2 < 2; nt2++)
                    b4n[nt2] = W4[((((kk + 1) << 4) + ntb + nt2) << 6) + lane];
            }
            short8 a8[4];
#pragma unroll
            for (int mt = 0; mt < 4; mt++) {
                int p = mt * 16 + m + dx;
                a8[mt] = *(const short8*)(st + (dy * 66 + p) * 136 + (cc << 5) + (ko << 3));
            }
            __builtin_amdgcn_s_setprio(1);
#pragma unroll
            for (int nt2 = 0; nt2 < 2; nt2++)
#pragma unroll
                for (int mt = 0; mt < 4; mt++)
                    acc[nt2][mt] = __builtin_amdgcn_mfma_f32_16x16x32_bf16(
                        a8[mt], *(short8*)&b4c[nt2], acc[nt2][mt], 0, 0, 0);
            __builtin_amdgcn_s_setprio(0);
            if (kk < 35) {
#pragma unroll
                for (int nt2 = 0; nt2 < 2; nt2++) b4c[nt2] = b4n[nt2];
            }
        }
    }
    __syncthreads();                       // stage reads done -> omT overlay safe
    // ---- phase 2: om tile -> LDS [px][217], single pass (wave owns its channels)
#pragma unroll
    for (int nt2 = 0; nt2 < 2; nt2++) {
        int o = (((w << 1) + nt2) << 4) + m;
        if (o < 216) {
            float bv = bom[o];
#pragma unroll
            for (int mt = 0; mt < 4; mt++) {
                f32x4 v = acc[nt2][mt];
#pragma unroll
                for (int r = 0; r < 4; r++)
                    omT[(mt * 16 + (ko << 2) + r) * 217 + o] = v[r] + bv;
            }
        }
    }
    __syncthreads();
    // ---- phase 3: DCN sampling, wave = (px quarter nq, K-half kh); 3-deep rolling
    const int nq = w & 3;
    const int kh = w >> 2;
    const int px = (nq << 4) + m;
    const float fh = (float)h, fw = (float)px;
    const int b14 = b << 14;
    const float* omrow = omT + px * 217;
    f32x4 accd[4];
#pragma unroll
    for (int nt = 0; nt < 4; nt++) accd[nt] = (f32x4){0.f, 0.f, 0.f, 0.f};
    {
        const int dk0 = kh * 18;
        uint4 s00[3], s01[3], s10[3], s11[3];
        float t00[3], t01[3], t10[3], t11[3];
#pragma unroll
        for (int i = 0; i < 2; i++)
            dcn_prep(dk0 + i, ko, omrow, fh, fw, fsC4, b14,
                     s00[i], s01[i], s10[i], s11[i], t00[i], t01[i], t10[i], t11[i]);
#pragma unroll
        for (int kki = 0; kki < 18; kki++) {
            const int sc_ = kki % 3;
            if (kki < 16) {
                const int sp = (kki + 2) % 3;
                dcn_prep(dk0 + kki + 2, ko, omrow, fh, fw, fsC4, b14,
                         s00[sp], s01[sp], s10[sp], s11[sp],
                         t00[sp], t01[sp], t10[sp], t11[sp]);
            }
            dcn_consume(dk0 + kki, s00[sc_], s01[sc_], s10[sc_], s11[sc_],
                        t00[sc_], t01[sc_], t10[sc_], t11[sc_], wbd4, lane, accd);
        }
    }
    __syncthreads();                       // omT reads done -> Rbuf overlay safe
    // ---- K-half reduction through Rbuf (stride 20 floats)
    if (kh == 1) {
#pragma unroll
        for (int nt = 0; nt < 4; nt++)
            *(f32x4*)(Rbuf + ((nq << 6) + lane) * 20 + (nt << 2)) = accd[nt];
    }
    __syncthreads();
    if (kh == 0) {
#pragma unroll
        for (int nt = 0; nt < 4; nt++)
            accd[nt] += *(const f32x4*)(Rbuf + ((nq << 6) + lane) * 20 + (nt << 2));
        // ---- phase 4a: align -> A3 bf16 [px][72]
#pragma unroll
        for (int nt = 0; nt < 4; nt++) {
            int o = (nt << 4) + m;
            float bv = bd[o];
#pragma unroll
            for (int r = 0; r < 4; r++) {
                float v = accd[nt][r] + bv;
                v = v > 0.f ? v : 0.f;
                A3[((nq << 4) + (ko << 2) + r) * 72 + o] = f2bf(v);
            }
        }
    }
    __syncthreads();                       // A3 visible to all waves
    // ---- phase 4b: cat GEMM K=64, N=128; wave = (px quarter nq, N-half kh)
    f32x4 acc2[4];
#pragma unroll
    for (int nt2 = 0; nt2 < 4; nt2++) acc2[nt2] = (f32x4){0.f, 0.f, 0.f, 0.f};
#pragma unroll
    for (int kk2 = 0; kk2 < 2; kk2++) {
        short8 av = *(const short8*)(A3 + ((nq << 4) + m) * 72 + kk2 * 32 + (ko << 3));
#pragma unroll
        for (int nt2 = 0; nt2 < 4; nt2++) {
            uint4 bu = ((const uint4*)wbc)[(kk2 * 8 + (kh << 2) + nt2) * 64 + lane];
            acc2[nt2] = __builtin_amdgcn_mfma_f32_16x16x32_bf16(av, *(short8*)&bu, acc2[nt2], 0, 0, 0);
        }
    }
    // ---- phase 4c: direct float4 epilogue (feat_arm preloaded, then fused store)
    {
        const int px0 = (nq << 4) + (ko << 2);
        const int base = (b << 19) + (h << 6) + px0;   // (b*128)<<12 + h*64 + px0
        f32x4 fa[4];
#pragma unroll
        for (int nt2 = 0; nt2 < 4; nt2++) {
            int o = (((kh << 2) + nt2) << 4) + m;
            fa[nt2] = *(const f32x4*)(feat_arm + base + (o << 12));
        }
#pragma unroll
        for (int nt2 = 0; nt2 < 4; nt2++) {
            int o = (((kh << 2) + nt2) << 4) + m;
            float sc = s_cat[o], bi = b_cat[o];
            f32x4 v;
#pragma unroll
            for (int r = 0; r < 4; r++) {
                float vv = fmaf(acc2[nt2][r], sc, bi);
                vv = vv > 0.f ? vv : 0.f;
                v[r] = vv + fa[nt2][r];
            }
            *(f32x4*)(feat + base + (o << 12)) = v;
        }
    }
}

extern "C" void kernel_launch(void* const* d_in, const int* in_sizes, int n_in,
                              void* d_out, int out_size, void* d_ws, size_t ws_size,
                              hipStream_t stream) {
    const float* feat_l = (const float*)d_in[0];
    const float* feat_s = (const float*)d_in[1];
    const float* W_fsm  = (const float*)d_in[2];
    const float* s_fsm  = (const float*)d_in[3];
    const float* b_fsm  = (const float*)d_in[4];
    const float* W_off  = (const float*)d_in[5];
    const float* s_off  = (const float*)d_in[6];
    const float* b_off  = (const float*)d_in[7];
    const float* W_om   = (const float*)d_in[8];
    const float* b_om   = (const float*)d_in[9];
    const float* W_dcn  = (const float*)d_in[10];
    const float* b_dcn  = (const float*)d_in[11];
    const float* W_cat  = (const float*)d_in[12];
    const float* s_cat  = (const float*)d_in[13];
    const float* b_cat  = (const float*)d_in[14];

    float* feat     = (float*)d_out;
    float* feat_arm = feat + 4194304;

    float* ws = (float*)d_ws;
    unsigned short* offT = (unsigned short*)ws;                // 2,097,152 f
    uint4* fsT4  = (uint4*)(ws + 9175040);                     //   524,288 f
    unsigned short* wb2   = (unsigned short*)(ws + 9699328);   //  147,456 f
    unsigned short* wbfsm = (unsigned short*)(ws + 9846784);   //    8,192 f
    unsigned short* wboff = (unsigned short*)(ws + 9854976);   //   16,384 f
    unsigned short* wbcat = (unsigned short*)(ws + 9871360);   //    4,096 f
    unsigned short* wbdcn = (unsigned short*)(ws + 9875456);   //   36,864 f
    uint4* fsC4  = (uint4*)(ws + 9912320);                     //   524,288 f

    k_prep<<<336, 256, 0, stream>>>(feat_s, fsT4, fsC4, W_fsm, W_off, W_cat,
                                    W_dcn, W_om, wbfsm, wboff, wbcat, wbdcn, wb2);

    k12<<<512, 512, 0, stream>>>(feat_l, fsT4, wbfsm, wboff,
                                 s_fsm, b_fsm, s_off, b_off, feat_arm, offT);
    k_omdcn<<<512, 512, 0, stream>>>(offT, fsC4, wb2, b_om, wbdcn, b_dcn,
                                     wbcat, s_cat, b_cat, feat_arm, feat);
}

// Round 4
// 159.036 us; speedup vs baseline: 1.1824x; 1.0141x over previous
//
#include <hip/hip_runtime.h>

// B=8, C=128, H=W=64, G=8, K=9, Cg=16, Cd=64. NCHW, HW=4096.
// MFMA conventions (verified in-problem, round 2):
//   A-frag: lane&15 = m, k-octet = (lane>>4)*8 + j
//   B-frag: lane&15 = n, k-octet = (lane>>4)*8 + j
//   C/D:    col = lane&15 (n), row = (lane>>4)*4 + r (m)
//
// Round-7 changes (L1/TA-throughput theory):
//  * k_omdcn phase 3: wave = (px-half, K-quarter) -> wbd B-frag reads deduped 4x->2x.
//  * wb2 packed N=14 tiles (was 16): wave 7 skips conv -> -12.5% conv W-traffic/MFMA.
//  * sigmoid hoisted to phase 2; om stored as oy/ox f32 + mask f16 (split arrays).
//  * k12: wave = (px-half, N-quarter) -> wbf/wbo reads halved.

typedef __attribute__((ext_vector_type(8))) short short8;
typedef __attribute__((ext_vector_type(4))) float f32x4;
typedef _Float16 __attribute__((ext_vector_type(2))) h2;

static __device__ __forceinline__ unsigned short f2bf(float x) {
    union { float f; unsigned int u; } v; v.f = x;
    return (unsigned short)((v.u + 0x7FFF + ((v.u >> 16) & 1)) >> 16);  // RNE
}
static __device__ __forceinline__ unsigned short f2h(float x) {
    union { _Float16 h; unsigned short u; } v; v.h = (_Float16)x;
    return v.u;
}

// ---------------- fused prep: blocks 0..127 = feat_s repack, 128..317 = weight packs
__global__ __launch_bounds__(256) void k_prep(const float* __restrict__ fs,
        uint4* __restrict__ fsT4, uint4* __restrict__ fsC4,
        const float* __restrict__ W_fsm, const float* __restrict__ W_off,
        const float* __restrict__ W_cat, const float* __restrict__ W_dcn,
        const float* __restrict__ W_om,
        unsigned short* __restrict__ wbfsm, unsigned short* __restrict__ wboff,
        unsigned short* __restrict__ wbcat, unsigned short* __restrict__ wbdcn,
        unsigned short* __restrict__ wb2) {
    __shared__ unsigned short st[64 * 136];
    const int t = threadIdx.x;
    if (blockIdx.x < 128) {
        unsigned int* st32 = (unsigned int*)st;
        const int b = blockIdx.x >> 4;
        const int p0 = (blockIdx.x & 15) << 6;
        for (int i = t; i < 64 * 64; i += 256) {
            int c2 = i >> 6, px = i & 63;
            float v0 = fs[(((b << 7) + 2 * c2) << 10) + p0 + px];
            float v1 = fs[(((b << 7) + 2 * c2 + 1) << 10) + p0 + px];
            st32[px * 68 + c2] = (unsigned int)f2bf(v0) | ((unsigned int)f2bf(v1) << 16);
        }
        __syncthreads();
        for (int i = t; i < 64 * 16; i += 256) {
            int px = i >> 4, q = i & 15;
            fsT4[(((b << 10) + p0 + px) << 4) + q] = ((const uint4*)(st + px * 136))[q];
        }
        __syncthreads();
        for (int i = t; i < 64 * 64; i += 256) {
            int c2 = i >> 6, px = i & 63;
            float v0 = fs[(((b << 7) + 2 * c2) << 10) + p0 + px];
            float v1 = fs[(((b << 7) + 2 * c2 + 1) << 10) + p0 + px];
            st32[px * 68 + c2] = (unsigned int)f2h(v0) | ((unsigned int)f2h(v1) << 16);
        }
        __syncthreads();
        // channel-major: fsC4[b][ci][p] , p = global fs pixel index (y2*32+x2)
        for (int i = t; i < 64 * 16; i += 256) {
            int ci = i >> 6, px = i & 63;
            fsC4[(b << 14) + (ci << 10) + p0 + px] = ((const uint4*)(st + px * 136))[ci];
        }
        return;
    }
    int idx = (blockIdx.x - 128) * 256 + t;
    int lane = idx & 63;
    int ml = lane & 15, kl = (lane >> 4) * 8;
    unsigned short tmp[8];
    if (idx < 2048) {                       // wbfsm: K=128, NT=8 (bf16)
        int r = idx >> 6;
        int o = (r % 8) * 16 + ml, k0 = (r / 8) * 32 + kl;
#pragma unroll
        for (int j = 0; j < 8; j++) tmp[j] = f2bf(W_fsm[o * 128 + k0 + j]);
        ((uint4*)wbfsm)[idx] = *(const uint4*)tmp;
    } else if (idx < 6144) {                // wboff: K=256, NT=8, x2 for k>=128 (bf16)
        int i2 = idx - 2048;
        int r = i2 >> 6;
        int o = (r % 8) * 16 + ml, k0 = (r / 8) * 32 + kl;
#pragma unroll
        for (int j = 0; j < 8; j++) {
            int k = k0 + j;
            float f = W_off[o * 256 + k];
            if (k >= 128) f *= 2.0f;
            tmp[j] = f2bf(f);
        }
        ((uint4*)wboff)[i2] = *(const uint4*)tmp;
    } else if (idx < 7168) {                // wbcat: K=64, NT=8 (bf16)
        int i2 = idx - 6144;
        int r = i2 >> 6;
        int o = (r % 8) * 16 + ml, k0 = (r / 8) * 32 + kl;
#pragma unroll
        for (int j = 0; j < 8; j++) tmp[j] = f2bf(W_cat[o * 64 + k0 + j]);
        ((uint4*)wbcat)[i2] = *(const uint4*)tmp;
    } else if (idx < 16384) {               // wbdcn: K=1152 (g,tap,c), NT=4 (f16)
        int i2 = idx - 7168;
        int r = i2 >> 6;
        int o = (r & 3) * 16 + ml, k0 = (r >> 2) * 32 + kl;
#pragma unroll
        for (int j = 0; j < 8; j++) {
            int k = k0 + j;
            int g = k / 144;
            int rem = k - g * 144;
            tmp[j] = f2h(W_dcn[(o * 128 + g * 16 + (rem & 15)) * 9 + (rem >> 4)]);
        }
        ((uint4*)wbdcn)[i2] = *(const uint4*)tmp;
    } else if (idx < 48640) {               // wb2: K=(tap,c), NT=14 (N=224, pad o>=216) bf16
        int i2 = idx - 16384;
        int r = i2 >> 6;
        int nt = r % 14, kk = r / 14;
        int tap = kk >> 2, cc = kk & 3;
        int o = nt * 16 + ml;
        int c0 = cc * 32 + kl;
#pragma unroll
        for (int j = 0; j < 8; j++) {
            float v = (o < 216) ? W_om[(o * 128 + (c0 + j)) * 9 + tap] : 0.0f;
            tmp[j] = f2bf(v);
        }
        ((uint4*)wb2)[i2] = *(const uint4*)tmp;
    }
}

// ---------------- k12: fused fsm GEMM (K=128) + off GEMM (K=256)
// 512 blocks x 8 waves. wave = (ph = px-half, nq4 = N-quarter):
// W-frag reads deduped 4x -> 2x; A reads double (LDS, cheap).
__global__ __launch_bounds__(512, 6) void k12(const float* __restrict__ feat_l,
        const uint4* __restrict__ fsT4,
        const unsigned short* __restrict__ wbf, const unsigned short* __restrict__ wbo,
        const float* __restrict__ s_fsm, const float* __restrict__ b_fsm,
        const float* __restrict__ s_off, const float* __restrict__ b_off,
        float* __restrict__ feat_arm, unsigned short* __restrict__ offT) {
    __shared__ unsigned short A1[64 * 136];
    __shared__ unsigned short A2[64 * 264];
    const int t = threadIdx.x;
    const int b = blockIdx.x >> 6;
    const int h = blockIdx.x & 63;
    const int hw0 = h << 6;
    unsigned int* A1w = (unsigned int*)A1;
    for (int i = t; i < 64 * 64; i += 512) {
        int c2 = i >> 6, px = i & 63;
        float v0 = feat_l[(((b << 7) + 2 * c2) << 12) + hw0 + px];
        float v1 = feat_l[(((b << 7) + 2 * c2 + 1) << 12) + hw0 + px];
        A1w[px * 68 + c2] = (unsigned int)f2bf(v0) | ((unsigned int)f2bf(v1) << 16);
    }
    {
        const int h2 = h >> 1;
        int px2 = t >> 4, q = t & 15;
        uint4 v = fsT4[(((b << 10) + (h2 << 5) + px2) << 4) + q];
        ((uint4*)(A2 + (2 * px2) * 264 + 128))[q] = v;
        ((uint4*)(A2 + (2 * px2 + 1) * 264 + 128))[q] = v;
    }
    __syncthreads();
    const int lane = t & 63;
    const int w = __builtin_amdgcn_readfirstlane(t >> 6);
    const int ph = w & 1;    // px half
    const int nq4 = w >> 1;  // N quarter
    const int m = lane & 15, ko = lane >> 4;
    f32x4 acc[2][2];   // [mt][nt2]
#pragma unroll
    for (int i = 0; i < 2; i++)
#pragma unroll
        for (int j = 0; j < 2; j++) acc[i][j] = (f32x4){0.f, 0.f, 0.f, 0.f};
#pragma unroll
    for (int kk = 0; kk < 4; kk++) {
        short8 a8[2];
#pragma unroll
        for (int mt = 0; mt < 2; mt++)
            a8[mt] = *(const short8*)(A1 + ((ph << 5) + (mt << 4) + m) * 136 + kk * 32 + ko * 8);
#pragma unroll
        for (int nt2 = 0; nt2 < 2; nt2++) {
            uint4 bu = ((const uint4*)wbf)[((kk << 3) + (nq4 << 1) + nt2) * 64 + lane];
#pragma unroll
            for (int mt = 0; mt < 2; mt++)
                acc[mt][nt2] = __builtin_amdgcn_mfma_f32_16x16x32_bf16(
                    a8[mt], *(short8*)&bu, acc[mt][nt2], 0, 0, 0);
        }
    }
    // fsm epilogue: bf16 -> A2 (off GEMM input) + direct float4 feat_arm store
#pragma unroll
    for (int nt2 = 0; nt2 < 2; nt2++) {
        int o = (((nq4 << 1) + nt2) << 4) + m;
        float sc = s_fsm[o], bi = b_fsm[o];
#pragma unroll
        for (int mt = 0; mt < 2; mt++) {
            int px0 = (ph << 5) + (mt << 4) + (ko << 2);
            f32x4 v;
#pragma unroll
            for (int r = 0; r < 4; r++) {
                float vv = fmaf(acc[mt][nt2][r], sc, bi);
                vv = vv > 0.f ? vv : 0.f;
                v[r] = vv;
                A2[(px0 + r) * 264 + o] = f2bf(vv);
            }
            *(f32x4*)(feat_arm + ((((b << 7) + o) << 12) + hw0 + px0)) = v;
        }
    }
    __syncthreads();
    f32x4 acc2[2][2];
#pragma unroll
    for (int i = 0; i < 2; i++)
#pragma unroll
        for (int j = 0; j < 2; j++) acc2[i][j] = (f32x4){0.f, 0.f, 0.f, 0.f};
#pragma unroll
    for (int kk = 0; kk < 8; kk++) {
        short8 a8[2];
#pragma unroll
        for (int mt = 0; mt < 2; mt++)
            a8[mt] = *(const short8*)(A2 + ((ph << 5) + (mt << 4) + m) * 264 + kk * 32 + ko * 8);
#pragma unroll
        for (int nt2 = 0; nt2 < 2; nt2++) {
            uint4 bu = ((const uint4*)wbo)[((kk << 3) + (nq4 << 1) + nt2) * 64 + lane];
#pragma unroll
            for (int mt = 0; mt < 2; mt++)
                acc2[mt][nt2] = __builtin_amdgcn_mfma_f32_16x16x32_bf16(
                    a8[mt], *(short8*)&bu, acc2[mt][nt2], 0, 0, 0);
        }
    }
    __syncthreads();
#pragma unroll
    for (int nt2 = 0; nt2 < 2; nt2++) {
        int o = (((nq4 << 1) + nt2) << 4) + m;
        float sc = s_off[o], bi = b_off[o];
#pragma unroll
        for (int mt = 0; mt < 2; mt++) {
            int px0 = (ph << 5) + (mt << 4) + (ko << 2);
#pragma unroll
            for (int r = 0; r < 4; r++) {
                float v = fmaf(acc2[mt][nt2][r], sc, bi);
                v = v > 0.f ? v : 0.f;
                A2[(px0 + r) * 264 + o] = f2bf(v);
            }
        }
    }
    __syncthreads();
    for (int i = t; i < 64 * 16; i += 512) {
        int px = i >> 4, q = i & 15;
        ((uint4*)offT)[(((b << 12) + hw0 + px) << 4) + q] = ((const uint4*)(A2 + px * 264))[q];
    }
}

// per-kk DCN gather prep for one pixel; mask already sigmoided (f16 in LDS)
static __device__ __forceinline__ void dcn_prep(int kk, int ko,
        const float* __restrict__ oyL, const float* __restrict__ oxL,
        const unsigned short* __restrict__ mskL, int px,
        float fh, const uint4* __restrict__ fsC4, int b14,
        uint4& c00, uint4& c01, uint4& c10, uint4& c11,
        float& w00, float& w01, float& w10, float& w11) {
    int k0 = (kk << 5) + (ko << 3);
    int g = k0 / 144;
    int rem = k0 - g * 144;
    int tap = rem >> 4;
    int c0 = rem & 15;
    int ch = g * 9 + tap;
    float oy = oyL[px * 73 + ch];
    float ox = oxL[px * 73 + ch];
    float mmv = (float)(*(const _Float16*)(mskL + px * 74 + ch));
    float py = fh + (float)(tap / 3 - 1) + oy;
    float pxx = (float)px + (float)(tap % 3 - 1) + ox;
    float y0f = floorf(py), x0f = floorf(pxx);
    float tyf = py - y0f, txf = pxx - x0f;
    int y0i = (int)y0f, x0i = (int)x0f;
    int y1i = y0i + 1, x1i = x0i + 1;
    bool vy0 = (y0i >= 0) && (y0i < 64);
    bool vy1 = (y1i >= 0) && (y1i < 64);
    bool vx0 = (x0i >= 0) && (x0i < 64);
    bool vx1 = (x1i >= 0) && (x1i < 64);
    w00 = (vy0 && vx0) ? (1.0f - tyf) * (1.0f - txf) * mmv : 0.0f;
    w01 = (vy0 && vx1) ? (1.0f - tyf) * txf * mmv : 0.0f;
    w10 = (vy1 && vx0) ? tyf * (1.0f - txf) * mmv : 0.0f;
    w11 = (vy1 && vx1) ? tyf * txf * mmv : 0.0f;
    int yc0 = y0i < 0 ? 0 : (y0i > 63 ? 63 : y0i);
    int yc1 = y1i < 0 ? 0 : (y1i > 63 ? 63 : y1i);
    int xc0 = x0i < 0 ? 0 : (x0i > 63 ? 63 : x0i);
    int xc1 = x1i < 0 ? 0 : (x1i > 63 ? 63 : x1i);
    int row0 = (yc0 >> 1) << 5, row1 = (yc1 >> 1) << 5;
    int ci = g * 2 + (c0 >> 3);
    const uint4* base = fsC4 + b14 + (ci << 10);
    c00 = base[row0 + (xc0 >> 1)];
    c01 = base[row0 + (xc1 >> 1)];
    c10 = base[row1 + (xc0 >> 1)];
    c11 = base[row1 + (xc1 >> 1)];
}

static __device__ __forceinline__ void dcn_consume(
        const uint4& c00, const uint4& c01, const uint4& c10, const uint4& c11,
        float w00, float w01, float w10, float w11,
        const uint4* __restrict__ wb, f32x4* accd) {
    _Float16 h00 = (_Float16)w00, h01 = (_Float16)w01;
    _Float16 h10 = (_Float16)w10, h11 = (_Float16)w11;
    h2 W00 = (h2){h00, h00}, W01 = (h2){h01, h01};
    h2 W10 = (h2){h10, h10}, W11 = (h2){h11, h11};
    union { uint4 u; h2 h[4]; } U00, U01, U10, U11;
    U00.u = c00; U01.u = c01; U10.u = c10; U11.u = c11;
    union { short8 s; h2 h[4]; } av;
#pragma unroll
    for (int c = 0; c < 4; c++)
        av.h[c] = U00.h[c] * W00 + U01.h[c] * W01 + U10.h[c] * W10 + U11.h[c] * W11;
    __builtin_amdgcn_s_setprio(1);
#pragma unroll
    for (int nt = 0; nt < 4; nt++) {
        uint4 bu = wb[nt * 64];
        accd[nt] = __builtin_amdgcn_mfma_f32_16x16x32_f16(av.s, *(short8*)&bu, accd[nt], 0, 0, 0);
    }
    __builtin_amdgcn_s_setprio(0);
}

// ---------------- k_omdcn: FUSED conv3x3(om) -> LDS -> DCNv2 sample -> cat GEMM -> feat
// 512 blocks (b, row h) x 8 waves (512 threads).
// LDS envelope 53,856 B (st). Overlays (all barrier-separated):
//   st: conv input stage                          0 .. 53,856 B
//   oyL f32[64][73] 0..18,688 | oxL 18,688..37,376 | mskL f16[64][74] 37,376..46,848
//   Rbuf (reduction) 0..36,864 | A3 bf16[64][72] at 36,864..46,080
__global__ __launch_bounds__(512, 4) void k_omdcn(
        const unsigned short* __restrict__ offT, const uint4* __restrict__ fsC4,
        const unsigned short* __restrict__ Wb2, const float* __restrict__ bom,
        const unsigned short* __restrict__ wbd, const float* __restrict__ bd,
        const unsigned short* __restrict__ wbc,
        const float* __restrict__ s_cat, const float* __restrict__ b_cat,
        const float* __restrict__ feat_arm, float* __restrict__ feat) {
    __shared__ float LDSf[13464];                          // 53,856 B
    unsigned short* st = (unsigned short*)LDSf;
    float* oyL = LDSf;                                     // [64][73]
    float* oxL = LDSf + 4672;                              // [64][73]
    unsigned short* mskL = (unsigned short*)(LDSf + 9344); // [64][74] f16
    float* Rbuf = LDSf;                                    // 4 slots x 64 x 36 f
    unsigned short* A3 = (unsigned short*)(LDSf + 9216);   // [64][72] bf16
    const uint4* offT4 = (const uint4*)offT;
    const uint4* W4 = (const uint4*)Wb2;
    const uint4* wbd4 = (const uint4*)wbd;
    const int t = threadIdx.x;
    const int b = blockIdx.x >> 6;
    const int h = blockIdx.x & 63;
    // ---- stage conv input rows h-1..h+1, 66 px, zero pad
    for (int i = t; i < 3 * 66 * 16; i += 512) {
        int q = i & 15;
        int rp = i >> 4;
        int r = rp / 66, p = rp - r * 66;
        int gy = h + r - 1, gx = p - 1;
        uint4 v = make_uint4(0, 0, 0, 0);
        if (gy >= 0 && gy < 64 && gx >= 0 && gx < 64)
            v = offT4[((((b << 6) + gy) << 6) + gx) * 16 + q];
        ((uint4*)(st + rp * 136))[q] = v;
    }
    __syncthreads();
    const int lane = t & 63;
    const int w = __builtin_amdgcn_readfirstlane(t >> 6);
    const int m = lane & 15, ko = lane >> 4;
    // ---- phase 1: conv3x3, N-split over 14 tiles: waves 0..6 own {2w,2w+1}; wave 7 idle
    f32x4 acc[2][4];   // [nt2][mt]
#pragma unroll
    for (int i = 0; i < 2; i++)
#pragma unroll
        for (int j = 0; j < 4; j++) acc[i][j] = (f32x4){0.f, 0.f, 0.f, 0.f};
    if (w < 7) {
        const int ntb = w << 1;
        uint4 b4c[2];
#pragma unroll
        for (int nt2 = 0; nt2 < 2; nt2++)
            b4c[nt2] = W4[((ntb + nt2) << 6) + lane];
#pragma unroll
        for (int kk = 0; kk < 36; kk++) {
            const int tap = kk >> 2, cc = kk & 3;
            const int dy = tap / 3, dx = tap - dy * 3;
            uint4 b4n[2];
            if (kk < 35) {
#pragma unroll
                for (int nt2 = 0; nt2 < 2; nt2++)
                    b4n[nt2] = W4[(((kk + 1) * 14 + ntb + nt2) << 6) + lane];
            }
            short8 a8[4];
#pragma unroll
            for (int mt = 0; mt < 4; mt++) {
                int p = mt * 16 + m + dx;
                a8[mt] = *(const short8*)(st + (dy * 66 + p) * 136 + (cc << 5) + (ko << 3));
            }
            __builtin_amdgcn_s_setprio(1);
#pragma unroll
            for (int nt2 = 0; nt2 < 2; nt2++)
#pragma unroll
                for (int mt = 0; mt < 4; mt++)
                    acc[nt2][mt] = __builtin_amdgcn_mfma_f32_16x16x32_bf16(
                        a8[mt], *(short8*)&b4c[nt2], acc[nt2][mt], 0, 0, 0);
            __builtin_amdgcn_s_setprio(0);
            if (kk < 35) {
#pragma unroll
                for (int nt2 = 0; nt2 < 2; nt2++) b4c[nt2] = b4n[nt2];
            }
        }
    }
    __syncthreads();                       // stage reads done -> om overlay safe
    // ---- phase 2: om -> split LDS; sigmoid applied to mask channels here
    if (w < 7) {
#pragma unroll
        for (int nt2 = 0; nt2 < 2; nt2++) {
            int o = (((w << 1) + nt2) << 4) + m;
            if (o < 216) {
                float bv = bom[o];
#pragma unroll
                for (int mt = 0; mt < 4; mt++) {
                    f32x4 v = acc[nt2][mt];
#pragma unroll
                    for (int r = 0; r < 4; r++) {
                        int px = mt * 16 + (ko << 2) + r;
                        float val = v[r] + bv;
                        if (o < 72) {
                            oyL[px * 73 + o] = val;
                        } else if (o < 144) {
                            oxL[px * 73 + (o - 72)] = val;
                        } else {
                            float sg = 1.0f / (1.0f + __expf(-val));
                            mskL[px * 74 + (o - 144)] = f2h(sg);
                        }
                    }
                }
            }
        }
    }
    __syncthreads();
    // ---- phase 3: DCN sampling, wave = (px-half mh, K-quarter kq), 9 kk, 2 px/lane
    const int mh = w & 1;
    const int kq = w >> 1;
    const float fh = (float)h;
    const int b14 = b << 14;
    f32x4 accd[2][4];  // [j][nt]
#pragma unroll
    for (int j = 0; j < 2; j++)
#pragma unroll
        for (int nt = 0; nt < 4; nt++) accd[j][nt] = (f32x4){0.f, 0.f, 0.f, 0.f};
    {
        const int dk0 = kq * 9;
        const int px0 = (mh << 5) + m;
#pragma unroll
        for (int kki = 0; kki < 9; kki++) {
            const int kk = dk0 + kki;
            uint4 a00, a01, a10, a11, e00, e01, e10, e11;
            float wa00, wa01, wa10, wa11, wb00, wb01, wb10, wb11;
            dcn_prep(kk, ko, oyL, oxL, mskL, px0, fh, fsC4, b14,
                     a00, a01, a10, a11, wa00, wa01, wa10, wa11);
            dcn_prep(kk, ko, oyL, oxL, mskL, px0 + 16, fh, fsC4, b14,
                     e00, e01, e10, e11, wb00, wb01, wb10, wb11);
            const uint4* wb = wbd4 + (kk << 2) * 64 + lane;
            dcn_consume(a00, a01, a10, a11, wa00, wa01, wa10, wa11, wb, accd[0]);
            dcn_consume(e00, e01, e10, e11, wb00, wb01, wb10, wb11, wb, accd[1]);
        }
    }
    __syncthreads();                       // om reads done -> Rbuf overlay safe
    // ---- reduction over 4 K-quarters, two rounds through Rbuf
    // slot(s,mh) base = ((s*2+mh)*64 + lane)*36 + j*16 + nt*4
    if (kq >= 2) {
        float* rb = Rbuf + ((((kq - 2) << 1) + mh) * 64 + lane) * 36;
#pragma unroll
        for (int j = 0; j < 2; j++)
#pragma unroll
            for (int nt = 0; nt < 4; nt++)
                *(f32x4*)(rb + (j << 4) + (nt << 2)) = accd[j][nt];
    }
    __syncthreads();
    if (kq < 2) {
        const float* rb = Rbuf + (((kq << 1) + mh) * 64 + lane) * 36;
#pragma unroll
        for (int j = 0; j < 2; j++)
#pragma unroll
            for (int nt = 0; nt < 4; nt++)
                accd[j][nt] += *(const f32x4*)(rb + (j << 4) + (nt << 2));
    }
    __syncthreads();
    if (kq == 1) {
        float* rb = Rbuf + (mh * 64 + lane) * 36;
#pragma unroll
        for (int j = 0; j < 2; j++)
#pragma unroll
            for (int nt = 0; nt < 4; nt++)
                *(f32x4*)(rb + (j << 4) + (nt << 2)) = accd[j][nt];
    }
    __syncthreads();
    if (kq == 0) {
        const float* rb = Rbuf + (mh * 64 + lane) * 36;
#pragma unroll
        for (int j = 0; j < 2; j++)
#pragma unroll
            for (int nt = 0; nt < 4; nt++)
                accd[j][nt] += *(const f32x4*)(rb + (j << 4) + (nt << 2));
        // ---- phase 4a: align -> A3 bf16 [px][72]
#pragma unroll
        for (int nt = 0; nt < 4; nt++) {
            int o = (nt << 4) + m;
            float bv = bd[o];
#pragma unroll
            for (int j = 0; j < 2; j++)
#pragma unroll
                for (int r = 0; r < 4; r++) {
                    float v = accd[j][nt][r] + bv;
                    v = v > 0.f ? v : 0.f;
                    A3[((mh << 5) + (j << 4) + (ko << 2) + r) * 72 + o] = f2bf(v);
                }
        }
    }
    __syncthreads();                       // A3 visible to all waves
    // ---- phase 4b: cat GEMM K=64, N=128; wave = (px-half mh, N-quarter kq)
    f32x4 acc2[2][2];  // [mt][nt2]
#pragma unroll
    for (int i = 0; i < 2; i++)
#pragma unroll
        for (int j = 0; j < 2; j++) acc2[i][j] = (f32x4){0.f, 0.f, 0.f, 0.f};
#pragma unroll
    for (int kk2 = 0; kk2 < 2; kk2++) {
        short8 a8[2];
#pragma unroll
        for (int mt = 0; mt < 2; mt++)
            a8[mt] = *(const short8*)(A3 + ((mh << 5) + (mt << 4) + m) * 72 + kk2 * 32 + (ko << 3));
#pragma unroll
        for (int nt2 = 0; nt2 < 2; nt2++) {
            uint4 bu = ((const uint4*)wbc)[((kk2 << 3) + (kq << 1) + nt2) * 64 + lane];
#pragma unroll
            for (int mt = 0; mt < 2; mt++)
                acc2[mt][nt2] = __builtin_amdgcn_mfma_f32_16x16x32_bf16(
                    a8[mt], *(short8*)&bu, acc2[mt][nt2], 0, 0, 0);
        }
    }
    // ---- phase 4c: direct float4 epilogue (feat_arm preload + fused store)
    {
#pragma unroll
        for (int nt2 = 0; nt2 < 2; nt2++) {
            int o = (((kq << 1) + nt2) << 4) + m;
            float sc = s_cat[o], bi = b_cat[o];
#pragma unroll
            for (int mt = 0; mt < 2; mt++) {
                int px0 = (mh << 5) + (mt << 4) + (ko << 2);
                int gidx = (b << 19) + (o << 12) + (h << 6) + px0;
                f32x4 fa = *(const f32x4*)(feat_arm + gidx);
                f32x4 v;
#pragma unroll
                for (int r = 0; r < 4; r++) {
                    float vv = fmaf(acc2[mt][nt2][r], sc, bi);
                    vv = vv > 0.f ? vv : 0.f;
                    v[r] = vv + fa[r];
                }
                *(f32x4*)(feat + gidx) = v;
            }
        }
    }
}

extern "C" void kernel_launch(void* const* d_in, const int* in_sizes, int n_in,
                              void* d_out, int out_size, void* d_ws, size_t ws_size,
                              hipStream_t stream) {
    const float* feat_l = (const float*)d_in[0];
    const float* feat_s = (const float*)d_in[1];
    const float* W_fsm  = (const float*)d_in[2];
    const float* s_fsm  = (const float*)d_in[3];
    const float* b_fsm  = (const float*)d_in[4];
    const float* W_off  = (const float*)d_in[5];
    const float* s_off  = (const float*)d_in[6];
    const float* b_off  = (const float*)d_in[7];
    const float* W_om   = (const float*)d_in[8];
    const float* b_om   = (const float*)d_in[9];
    const float* W_dcn  = (const float*)d_in[10];
    const float* b_dcn  = (const float*)d_in[11];
    const float* W_cat  = (const float*)d_in[12];
    const float* s_cat  = (const float*)d_in[13];
    const float* b_cat  = (const float*)d_in[14];

    float* feat     = (float*)d_out;
    float* feat_arm = feat + 4194304;

    float* ws = (float*)d_ws;
    unsigned short* offT = (unsigned short*)ws;                // 2,097,152 f
    uint4* fsT4  = (uint4*)(ws + 9175040);                     //   524,288 f
    unsigned short* wb2   = (unsigned short*)(ws + 9699328);   //  147,456 f
    unsigned short* wbfsm = (unsigned short*)(ws + 9846784);   //    8,192 f
    unsigned short* wboff = (unsigned short*)(ws + 9854976);   //   16,384 f
    unsigned short* wbcat = (unsigned short*)(ws + 9871360);   //    4,096 f
    unsigned short* wbdcn = (unsigned short*)(ws + 9875456);   //   36,864 f
    uint4* fsC4  = (uint4*)(ws + 9912320);                     //   524,288 f

    k_prep<<<318, 256, 0, stream>>>(feat_s, fsT4, fsC4, W_fsm, W_off, W_cat,
                                    W_dcn, W_om, wbfsm, wboff, wbcat, wbdcn, wb2);

    k12<<<512, 512, 0, stream>>>(feat_l, fsT4, wbfsm, wboff,
                                 s_fsm, b_fsm, s_off, b_off, feat_arm, offT);
    k_omdcn<<<512, 512, 0, stream>>>(offT, fsC4, wb2, b_om, wbdcn, b_dcn,
                                     wbcat, s_cat, b_cat, feat_arm, feat);
}

// Round 5
// 158.121 us; speedup vs baseline: 1.1892x; 1.0058x over previous
//
#include <hip/hip_runtime.h>

// B=8, C=128, H=W=64, G=8, K=9, Cg=16, Cd=64. NCHW, HW=4096.
// MFMA conventions (verified in-problem, round 2):
//   A-frag: lane&15 = m, k-octet = (lane>>4)*8 + j
//   B-frag: lane&15 = n, k-octet = (lane>>4)*8 + j
//   C/D:    col = lane&15 (n), row = (lane>>4)*4 + r (m)
//
// Round-8: recombine measured winners.
//  * k12: round-3 version (px-half x N-quarter, W-reads deduped) - measured win.
//  * k_omdcn phase 3/reduction: REVERTED to round-2 structure (px-quarter x K-half,
//    rolling pipeline, 1-round Rbuf reduction) - measured 52.2-52.4 us.
//  * Kept: NT=14 conv packing (waves 0-6), sigmoid hoisted to phase-2 omT write
//    (unified f32 [64][217], mask channels stored post-sigmoid).

typedef __attribute__((ext_vector_type(8))) short short8;
typedef __attribute__((ext_vector_type(4))) float f32x4;
typedef _Float16 __attribute__((ext_vector_type(2))) h2;

static __device__ __forceinline__ unsigned short f2bf(float x) {
    union { float f; unsigned int u; } v; v.f = x;
    return (unsigned short)((v.u + 0x7FFF + ((v.u >> 16) & 1)) >> 16);  // RNE
}
static __device__ __forceinline__ unsigned short f2h(float x) {
    union { _Float16 h; unsigned short u; } v; v.h = (_Float16)x;
    return v.u;
}

// ---------------- fused prep: blocks 0..127 = feat_s repack, 128..317 = weight packs
__global__ __launch_bounds__(256) void k_prep(const float* __restrict__ fs,
        uint4* __restrict__ fsT4, uint4* __restrict__ fsC4,
        const float* __restrict__ W_fsm, const float* __restrict__ W_off,
        const float* __restrict__ W_cat, const float* __restrict__ W_dcn,
        const float* __restrict__ W_om,
        unsigned short* __restrict__ wbfsm, unsigned short* __restrict__ wboff,
        unsigned short* __restrict__ wbcat, unsigned short* __restrict__ wbdcn,
        unsigned short* __restrict__ wb2) {
    __shared__ unsigned short st[64 * 136];
    const int t = threadIdx.x;
    if (blockIdx.x < 128) {
        unsigned int* st32 = (unsigned int*)st;
        const int b = blockIdx.x >> 4;
        const int p0 = (blockIdx.x & 15) << 6;
        for (int i = t; i < 64 * 64; i += 256) {
            int c2 = i >> 6, px = i & 63;
            float v0 = fs[(((b << 7) + 2 * c2) << 10) + p0 + px];
            float v1 = fs[(((b << 7) + 2 * c2 + 1) << 10) + p0 + px];
            st32[px * 68 + c2] = (unsigned int)f2bf(v0) | ((unsigned int)f2bf(v1) << 16);
        }
        __syncthreads();
        for (int i = t; i < 64 * 16; i += 256) {
            int px = i >> 4, q = i & 15;
            fsT4[(((b << 10) + p0 + px) << 4) + q] = ((const uint4*)(st + px * 136))[q];
        }
        __syncthreads();
        for (int i = t; i < 64 * 64; i += 256) {
            int c2 = i >> 6, px = i & 63;
            float v0 = fs[(((b << 7) + 2 * c2) << 10) + p0 + px];
            float v1 = fs[(((b << 7) + 2 * c2 + 1) << 10) + p0 + px];
            st32[px * 68 + c2] = (unsigned int)f2h(v0) | ((unsigned int)f2h(v1) << 16);
        }
        __syncthreads();
        // channel-major: fsC4[b][ci][p] , p = global fs pixel index (y2*32+x2)
        for (int i = t; i < 64 * 16; i += 256) {
            int ci = i >> 6, px = i & 63;
            fsC4[(b << 14) + (ci << 10) + p0 + px] = ((const uint4*)(st + px * 136))[ci];
        }
        return;
    }
    int idx = (blockIdx.x - 128) * 256 + t;
    int lane = idx & 63;
    int ml = lane & 15, kl = (lane >> 4) * 8;
    unsigned short tmp[8];
    if (idx < 2048) {                       // wbfsm: K=128, NT=8 (bf16)
        int r = idx >> 6;
        int o = (r % 8) * 16 + ml, k0 = (r / 8) * 32 + kl;
#pragma unroll
        for (int j = 0; j < 8; j++) tmp[j] = f2bf(W_fsm[o * 128 + k0 + j]);
        ((uint4*)wbfsm)[idx] = *(const uint4*)tmp;
    } else if (idx < 6144) {                // wboff: K=256, NT=8, x2 for k>=128 (bf16)
        int i2 = idx - 2048;
        int r = i2 >> 6;
        int o = (r % 8) * 16 + ml, k0 = (r / 8) * 32 + kl;
#pragma unroll
        for (int j = 0; j < 8; j++) {
            int k = k0 + j;
            float f = W_off[o * 256 + k];
            if (k >= 128) f *= 2.0f;
            tmp[j] = f2bf(f);
        }
        ((uint4*)wboff)[i2] = *(const uint4*)tmp;
    } else if (idx < 7168) {                // wbcat: K=64, NT=8 (bf16)
        int i2 = idx - 6144;
        int r = i2 >> 6;
        int o = (r % 8) * 16 + ml, k0 = (r / 8) * 32 + kl;
#pragma unroll
        for (int j = 0; j < 8; j++) tmp[j] = f2bf(W_cat[o * 64 + k0 + j]);
        ((uint4*)wbcat)[i2] = *(const uint4*)tmp;
    } else if (idx < 16384) {               // wbdcn: K=1152 (g,tap,c), NT=4 (f16)
        int i2 = idx - 7168;
        int r = i2 >> 6;
        int o = (r & 3) * 16 + ml, k0 = (r >> 2) * 32 + kl;
#pragma unroll
        for (int j = 0; j < 8; j++) {
            int k = k0 + j;
            int g = k / 144;
            int rem = k - g * 144;
            tmp[j] = f2h(W_dcn[(o * 128 + g * 16 + (rem & 15)) * 9 + (rem >> 4)]);
        }
        ((uint4*)wbdcn)[i2] = *(const uint4*)tmp;
    } else if (idx < 48640) {               // wb2: K=(tap,c), NT=14 (N=224, pad o>=216) bf16
        int i2 = idx - 16384;
        int r = i2 >> 6;
        int nt = r % 14, kk = r / 14;
        int tap = kk >> 2, cc = kk & 3;
        int o = nt * 16 + ml;
        int c0 = cc * 32 + kl;
#pragma unroll
        for (int j = 0; j < 8; j++) {
            float v = (o < 216) ? W_om[(o * 128 + (c0 + j)) * 9 + tap] : 0.0f;
            tmp[j] = f2bf(v);
        }
        ((uint4*)wb2)[i2] = *(const uint4*)tmp;
    }
}

// ---------------- k12: fused fsm GEMM (K=128) + off GEMM (K=256)
// 512 blocks x 8 waves. wave = (ph = px-half, nq4 = N-quarter):
// W-frag reads deduped 4x -> 2x; A reads double (LDS, cheap).
__global__ __launch_bounds__(512, 6) void k12(const float* __restrict__ feat_l,
        const uint4* __restrict__ fsT4,
        const unsigned short* __restrict__ wbf, const unsigned short* __restrict__ wbo,
        const float* __restrict__ s_fsm, const float* __restrict__ b_fsm,
        const float* __restrict__ s_off, const float* __restrict__ b_off,
        float* __restrict__ feat_arm, unsigned short* __restrict__ offT) {
    __shared__ unsigned short A1[64 * 136];
    __shared__ unsigned short A2[64 * 264];
    const int t = threadIdx.x;
    const int b = blockIdx.x >> 6;
    const int h = blockIdx.x & 63;
    const int hw0 = h << 6;
    unsigned int* A1w = (unsigned int*)A1;
    for (int i = t; i < 64 * 64; i += 512) {
        int c2 = i >> 6, px = i & 63;
        float v0 = feat_l[(((b << 7) + 2 * c2) << 12) + hw0 + px];
        float v1 = feat_l[(((b << 7) + 2 * c2 + 1) << 12) + hw0 + px];
        A1w[px * 68 + c2] = (unsigned int)f2bf(v0) | ((unsigned int)f2bf(v1) << 16);
    }
    {
        const int h2 = h >> 1;
        int px2 = t >> 4, q = t & 15;
        uint4 v = fsT4[(((b << 10) + (h2 << 5) + px2) << 4) + q];
        ((uint4*)(A2 + (2 * px2) * 264 + 128))[q] = v;
        ((uint4*)(A2 + (2 * px2 + 1) * 264 + 128))[q] = v;
    }
    __syncthreads();
    const int lane = t & 63;
    const int w = __builtin_amdgcn_readfirstlane(t >> 6);
    const int ph = w & 1;    // px half
    const int nq4 = w >> 1;  // N quarter
    const int m = lane & 15, ko = lane >> 4;
    f32x4 acc[2][2];   // [mt][nt2]
#pragma unroll
    for (int i = 0; i < 2; i++)
#pragma unroll
        for (int j = 0; j < 2; j++) acc[i][j] = (f32x4){0.f, 0.f, 0.f, 0.f};
#pragma unroll
    for (int kk = 0; kk < 4; kk++) {
        short8 a8[2];
#pragma unroll
        for (int mt = 0; mt < 2; mt++)
            a8[mt] = *(const short8*)(A1 + ((ph << 5) + (mt << 4) + m) * 136 + kk * 32 + ko * 8);
#pragma unroll
        for (int nt2 = 0; nt2 < 2; nt2++) {
            uint4 bu = ((const uint4*)wbf)[((kk << 3) + (nq4 << 1) + nt2) * 64 + lane];
#pragma unroll
            for (int mt = 0; mt < 2; mt++)
                acc[mt][nt2] = __builtin_amdgcn_mfma_f32_16x16x32_bf16(
                    a8[mt], *(short8*)&bu, acc[mt][nt2], 0, 0, 0);
        }
    }
    // fsm epilogue: bf16 -> A2 (off GEMM input) + direct float4 feat_arm store
#pragma unroll
    for (int nt2 = 0; nt2 < 2; nt2++) {
        int o = (((nq4 << 1) + nt2) << 4) + m;
        float sc = s_fsm[o], bi = b_fsm[o];
#pragma unroll
        for (int mt = 0; mt < 2; mt++) {
            int px0 = (ph << 5) + (mt << 4) + (ko << 2);
            f32x4 v;
#pragma unroll
            for (int r = 0; r < 4; r++) {
                float vv = fmaf(acc[mt][nt2][r], sc, bi);
                vv = vv > 0.f ? vv : 0.f;
                v[r] = vv;
                A2[(px0 + r) * 264 + o] = f2bf(vv);
            }
            *(f32x4*)(feat_arm + ((((b << 7) + o) << 12) + hw0 + px0)) = v;
        }
    }
    __syncthreads();
    f32x4 acc2[2][2];
#pragma unroll
    for (int i = 0; i < 2; i++)
#pragma unroll
        for (int j = 0; j < 2; j++) acc2[i][j] = (f32x4){0.f, 0.f, 0.f, 0.f};
#pragma unroll
    for (int kk = 0; kk < 8; kk++) {
        short8 a8[2];
#pragma unroll
        for (int mt = 0; mt < 2; mt++)
            a8[mt] = *(const short8*)(A2 + ((ph << 5) + (mt << 4) + m) * 264 + kk * 32 + ko * 8);
#pragma unroll
        for (int nt2 = 0; nt2 < 2; nt2++) {
            uint4 bu = ((const uint4*)wbo)[((kk << 3) + (nq4 << 1) + nt2) * 64 + lane];
#pragma unroll
            for (int mt = 0; mt < 2; mt++)
                acc2[mt][nt2] = __builtin_amdgcn_mfma_f32_16x16x32_bf16(
                    a8[mt], *(short8*)&bu, acc2[mt][nt2], 0, 0, 0);
        }
    }
    __syncthreads();
#pragma unroll
    for (int nt2 = 0; nt2 < 2; nt2++) {
        int o = (((nq4 << 1) + nt2) << 4) + m;
        float sc = s_off[o], bi = b_off[o];
#pragma unroll
        for (int mt = 0; mt < 2; mt++) {
            int px0 = (ph << 5) + (mt << 4) + (ko << 2);
#pragma unroll
            for (int r = 0; r < 4; r++) {
                float v = fmaf(acc2[mt][nt2][r], sc, bi);
                v = v > 0.f ? v : 0.f;
                A2[(px0 + r) * 264 + o] = f2bf(v);
            }
        }
    }
    __syncthreads();
    for (int i = t; i < 64 * 16; i += 512) {
        int px = i >> 4, q = i & 15;
        ((uint4*)offT)[(((b << 12) + hw0 + px) << 4) + q] = ((const uint4*)(A2 + px * 264))[q];
    }
}

// per-kk DCN gather prep: bilinear weights (mask pre-sigmoided in omT) + 4 gathers
static __device__ __forceinline__ void dcn_prep(int kk, int ko, const float* omrow,
        float fh, float fw, const uint4* __restrict__ fsC4, int b14,
        uint4& c00, uint4& c01, uint4& c10, uint4& c11,
        float& w00, float& w01, float& w10, float& w11) {
    int k0 = (kk << 5) + (ko << 3);
    int g = k0 / 144;
    int rem = k0 - g * 144;
    int tap = rem >> 4;
    int c0 = rem & 15;
    int ch = g * 9 + tap;
    float oy = omrow[ch];
    float ox = omrow[72 + ch];
    float mmv = omrow[144 + ch];            // already sigmoided (phase 2)
    float py = fh + (float)(tap / 3 - 1) + oy;
    float pxx = fw + (float)(tap % 3 - 1) + ox;
    float y0f = floorf(py), x0f = floorf(pxx);
    float tyf = py - y0f, txf = pxx - x0f;
    int y0i = (int)y0f, x0i = (int)x0f;
    int y1i = y0i + 1, x1i = x0i + 1;
    bool vy0 = (y0i >= 0) && (y0i < 64);
    bool vy1 = (y1i >= 0) && (y1i < 64);
    bool vx0 = (x0i >= 0) && (x0i < 64);
    bool vx1 = (x1i >= 0) && (x1i < 64);
    w00 = (vy0 && vx0) ? (1.0f - tyf) * (1.0f - txf) * mmv : 0.0f;
    w01 = (vy0 && vx1) ? (1.0f - tyf) * txf * mmv : 0.0f;
    w10 = (vy1 && vx0) ? tyf * (1.0f - txf) * mmv : 0.0f;
    w11 = (vy1 && vx1) ? tyf * txf * mmv : 0.0f;
    int yc0 = y0i < 0 ? 0 : (y0i > 63 ? 63 : y0i);
    int yc1 = y1i < 0 ? 0 : (y1i > 63 ? 63 : y1i);
    int xc0 = x0i < 0 ? 0 : (x0i > 63 ? 63 : x0i);
    int xc1 = x1i < 0 ? 0 : (x1i > 63 ? 63 : x1i);
    int row0 = (yc0 >> 1) << 5, row1 = (yc1 >> 1) << 5;
    int ci = g * 2 + (c0 >> 3);
    const uint4* base = fsC4 + b14 + (ci << 10);
    c00 = base[row0 + (xc0 >> 1)];
    c01 = base[row0 + (xc1 >> 1)];
    c10 = base[row1 + (xc0 >> 1)];
    c11 = base[row1 + (xc1 >> 1)];
}

static __device__ __forceinline__ void dcn_consume(int kk,
        const uint4& c00, const uint4& c01, const uint4& c10, const uint4& c11,
        float w00, float w01, float w10, float w11,
        const uint4* __restrict__ wbd4, int lane, f32x4* accd) {
    _Float16 h00 = (_Float16)w00, h01 = (_Float16)w01;
    _Float16 h10 = (_Float16)w10, h11 = (_Float16)w11;
    h2 W00 = (h2){h00, h00}, W01 = (h2){h01, h01};
    h2 W10 = (h2){h10, h10}, W11 = (h2){h11, h11};
    union { uint4 u; h2 h[4]; } U00, U01, U10, U11;
    U00.u = c00; U01.u = c01; U10.u = c10; U11.u = c11;
    union { short8 s; h2 h[4]; } av;
#pragma unroll
    for (int c = 0; c < 4; c++)
        av.h[c] = U00.h[c] * W00 + U01.h[c] * W01 + U10.h[c] * W10 + U11.h[c] * W11;
    const uint4* wb = wbd4 + (kk << 2) * 64 + lane;
    __builtin_amdgcn_s_setprio(1);
#pragma unroll
    for (int nt = 0; nt < 4; nt++) {
        uint4 bu = wb[nt * 64];
        accd[nt] = __builtin_amdgcn_mfma_f32_16x16x32_f16(av.s, *(short8*)&bu, accd[nt], 0, 0, 0);
    }
    __builtin_amdgcn_s_setprio(0);
}

// ---------------- k_omdcn: FUSED conv3x3(om) -> LDS -> DCNv2 sample -> cat GEMM -> feat
// 512 blocks (b, row h) x 8 waves (512 threads).
// Phase 1 (conv): N-split over 14 tiles (waves 0..6 own {2w,2w+1}; wave 7 idle).
// Phase 2: single-pass omT write (+bias, sigmoid on mask channels) f32 [64][217].
// Phase 3 (DCN): wave = (px-quarter nq, K-half kh); rolling 3-deep gather pipeline;
//                partials reduced via Rbuf (stride 20, overlays omT after barrier).
// Phase 4: cat GEMM (K=64) N-split across kh; DIRECT float4 epilogue stores.
__global__ __launch_bounds__(512, 4) void k_omdcn(
        const unsigned short* __restrict__ offT, const uint4* __restrict__ fsC4,
        const unsigned short* __restrict__ Wb2, const float* __restrict__ bom,
        const unsigned short* __restrict__ wbd, const float* __restrict__ bd,
        const unsigned short* __restrict__ wbc,
        const float* __restrict__ s_cat, const float* __restrict__ b_cat,
        const float* __restrict__ feat_arm, float* __restrict__ feat) {
    __shared__ float LDSf[16384];                          // 64 KiB (2 blocks/CU)
    unsigned short* st = (unsigned short*)LDSf;            // 53,856 B conv input stage
    float* omT = LDSf;                                     // 64*217*4 = 55,552 B (overlay)
    float* Rbuf = LDSf;                                    // overlay, post-P3 (20.5 KB)
    unsigned short* A3 = (unsigned short*)(LDSf + 13888);  // 64*72*2 = 9,216 B (separate)
    const uint4* offT4 = (const uint4*)offT;
    const uint4* W4 = (const uint4*)Wb2;
    const uint4* wbd4 = (const uint4*)wbd;
    const int t = threadIdx.x;
    const int b = blockIdx.x >> 6;
    const int h = blockIdx.x & 63;
    // ---- stage conv input rows h-1..h+1, 66 px, zero pad
    for (int i = t; i < 3 * 66 * 16; i += 512) {
        int q = i & 15;
        int rp = i >> 4;
        int r = rp / 66, p = rp - r * 66;
        int gy = h + r - 1, gx = p - 1;
        uint4 v = make_uint4(0, 0, 0, 0);
        if (gy >= 0 && gy < 64 && gx >= 0 && gx < 64)
            v = offT4[((((b << 6) + gy) << 6) + gx) * 16 + q];
        ((uint4*)(st + rp * 136))[q] = v;
    }
    __syncthreads();
    const int lane = t & 63;
    const int w = __builtin_amdgcn_readfirstlane(t >> 6);
    const int m = lane & 15, ko = lane >> 4;
    // ---- phase 1: conv3x3, N-split over 14 tiles: waves 0..6 own {2w,2w+1}
    f32x4 acc[2][4];   // [nt2][mt]
#pragma unroll
    for (int i = 0; i < 2; i++)
#pragma unroll
        for (int j = 0; j < 4; j++) acc[i][j] = (f32x4){0.f, 0.f, 0.f, 0.f};
    if (w < 7) {
        const int ntb = w << 1;
        uint4 b4c[2];
#pragma unroll
        for (int nt2 = 0; nt2 < 2; nt2++)
            b4c[nt2] = W4[((ntb + nt2) << 6) + lane];
#pragma unroll
        for (int kk = 0; kk < 36; kk++) {
            const int tap = kk >> 2, cc = kk & 3;
            const int dy = tap / 3, dx = tap - dy * 3;
            uint4 b4n[2];
            if (kk < 35) {
#pragma unroll
                for (int nt2 = 0; nt2 < 2; nt2++)
                    b4n[nt2] = W4[(((kk + 1) * 14 + ntb + nt2) << 6) + lane];
            }
            short8 a8[4];
#pragma unroll
            for (int mt = 0; mt < 4; mt++) {
                int p = mt * 16 + m + dx;
                a8[mt] = *(const short8*)(st + (dy * 66 + p) * 136 + (cc << 5) + (ko << 3));
            }
            __builtin_amdgcn_s_setprio(1);
#pragma unroll
            for (int nt2 = 0; nt2 < 2; nt2++)
#pragma unroll
                for (int mt = 0; mt < 4; mt++)
                    acc[nt2][mt] = __builtin_amdgcn_mfma_f32_16x16x32_bf16(
                        a8[mt], *(short8*)&b4c[nt2], acc[nt2][mt], 0, 0, 0);
            __builtin_amdgcn_s_setprio(0);
            if (kk < 35) {
#pragma unroll
                for (int nt2 = 0; nt2 < 2; nt2++) b4c[nt2] = b4n[nt2];
            }
        }
    }
    __syncthreads();                       // stage reads done -> omT overlay safe
    // ---- phase 2: om tile -> LDS [px][217]; sigmoid applied to mask channels
    if (w < 7) {
#pragma unroll
        for (int nt2 = 0; nt2 < 2; nt2++) {
            int o = (((w << 1) + nt2) << 4) + m;
            if (o < 216) {
                float bv = bom[o];
                bool ismask = (o >= 144);
#pragma unroll
                for (int mt = 0; mt < 4; mt++) {
                    f32x4 v = acc[nt2][mt];
#pragma unroll
                    for (int r = 0; r < 4; r++) {
                        float val = v[r] + bv;
                        if (ismask) val = 1.0f / (1.0f + __expf(-val));
                        omT[(mt * 16 + (ko << 2) + r) * 217 + o] = val;
                    }
                }
            }
        }
    }
    __syncthreads();
    // ---- phase 3: DCN sampling, wave = (px quarter nq, K-half kh); 3-deep rolling
    const int nq = w & 3;
    const int kh = w >> 2;
    const int px = (nq << 4) + m;
    const float fh = (float)h, fw = (float)px;
    const int b14 = b << 14;
    const float* omrow = omT + px * 217;
    f32x4 accd[4];
#pragma unroll
    for (int nt = 0; nt < 4; nt++) accd[nt] = (f32x4){0.f, 0.f, 0.f, 0.f};
    {
        const int dk0 = kh * 18;
        uint4 s00[3], s01[3], s10[3], s11[3];
        float t00[3], t01[3], t10[3], t11[3];
#pragma unroll
        for (int i = 0; i < 2; i++)
            dcn_prep(dk0 + i, ko, omrow, fh, fw, fsC4, b14,
                     s00[i], s01[i], s10[i], s11[i], t00[i], t01[i], t10[i], t11[i]);
#pragma unroll
        for (int kki = 0; kki < 18; kki++) {
            const int sc_ = kki % 3;
            if (kki < 16) {
                const int sp = (kki + 2) % 3;
                dcn_prep(dk0 + kki + 2, ko, omrow, fh, fw, fsC4, b14,
                         s00[sp], s01[sp], s10[sp], s11[sp],
                         t00[sp], t01[sp], t10[sp], t11[sp]);
            }
            dcn_consume(dk0 + kki, s00[sc_], s01[sc_], s10[sc_], s11[sc_],
                        t00[sc_], t01[sc_], t10[sc_], t11[sc_], wbd4, lane, accd);
        }
    }
    __syncthreads();                       // omT reads done -> Rbuf overlay safe
    // ---- K-half reduction through Rbuf (stride 20 floats)
    if (kh == 1) {
#pragma unroll
        for (int nt = 0; nt < 4; nt++)
            *(f32x4*)(Rbuf + ((nq << 6) + lane) * 20 + (nt << 2)) = accd[nt];
    }
    __syncthreads();
    if (kh == 0) {
#pragma unroll
        for (int nt = 0; nt < 4; nt++)
            accd[nt] += *(const f32x4*)(Rbuf + ((nq << 6) + lane) * 20 + (nt << 2));
        // ---- phase 4a: align -> A3 bf16 [px][72]
#pragma unroll
        for (int nt = 0; nt < 4; nt++) {
            int o = (nt << 4) + m;
            float bv = bd[o];
#pragma unroll
            for (int r = 0; r < 4; r++) {
                float v = accd[nt][r] + bv;
                v = v > 0.f ? v : 0.f;
                A3[((nq << 4) + (ko << 2) + r) * 72 + o] = f2bf(v);
            }
        }
    }
    __syncthreads();                       // A3 visible to all waves
    // ---- phase 4b: cat GEMM K=64, N=128; wave = (px quarter nq, N-half kh)
    f32x4 acc2[4];
#pragma unroll
    for (int nt2 = 0; nt2 < 4; nt2++) acc2[nt2] = (f32x4){0.f, 0.f, 0.f, 0.f};
#pragma unroll
    for (int kk2 = 0; kk2 < 2; kk2++) {
        short8 av = *(const short8*)(A3 + ((nq << 4) + m) * 72 + kk2 * 32 + (ko << 3));
#pragma unroll
        for (int nt2 = 0; nt2 < 4; nt2++) {
            uint4 bu = ((const uint4*)wbc)[(kk2 * 8 + (kh << 2) + nt2) * 64 + lane];
            acc2[nt2] = __builtin_amdgcn_mfma_f32_16x16x32_bf16(av, *(short8*)&bu, acc2[nt2], 0, 0, 0);
        }
    }
    // ---- phase 4c: direct float4 epilogue (feat_arm preload + fused store)
    {
        const int px0 = (nq << 4) + (ko << 2);
        const int base = (b << 19) + (h << 6) + px0;
        f32x4 fa[4];
#pragma unroll
        for (int nt2 = 0; nt2 < 4; nt2++) {
            int o = (((kh << 2) + nt2) << 4) + m;
            fa[nt2] = *(const f32x4*)(feat_arm + base + (o << 12));
        }
#pragma unroll
        for (int nt2 = 0; nt2 < 4; nt2++) {
            int o = (((kh << 2) + nt2) << 4) + m;
            float sc = s_cat[o], bi = b_cat[o];
            f32x4 v;
#pragma unroll
            for (int r = 0; r < 4; r++) {
                float vv = fmaf(acc2[nt2][r], sc, bi);
                vv = vv > 0.f ? vv : 0.f;
                v[r] = vv + fa[nt2][r];
            }
            *(f32x4*)(feat + base + (o << 12)) = v;
        }
    }
}

extern "C" void kernel_launch(void* const* d_in, const int* in_sizes, int n_in,
                              void* d_out, int out_size, void* d_ws, size_t ws_size,
                              hipStream_t stream) {
    const float* feat_l = (const float*)d_in[0];
    const float* feat_s = (const float*)d_in[1];
    const float* W_fsm  = (const float*)d_in[2];
    const float* s_fsm  = (const float*)d_in[3];
    const float* b_fsm  = (const float*)d_in[4];
    const float* W_off  = (const float*)d_in[5];
    const float* s_off  = (const float*)d_in[6];
    const float* b_off  = (const float*)d_in[7];
    const float* W_om   = (const float*)d_in[8];
    const float* b_om   = (const float*)d_in[9];
    const float* W_dcn  = (const float*)d_in[10];
    const float* b_dcn  = (const float*)d_in[11];
    const float* W_cat  = (const float*)d_in[12];
    const float* s_cat  = (const float*)d_in[13];
    const float* b_cat  = (const float*)d_in[14];

    float* feat     = (float*)d_out;
    float* feat_arm = feat + 4194304;

    float* ws = (float*)d_ws;
    unsigned short* offT = (unsigned short*)ws;                // 2,097,152 f
    uint4* fsT4  = (uint4*)(ws + 9175040);                     //   524,288 f
    unsigned short* wb2   = (unsigned short*)(ws + 9699328);   //  147,456 f
    unsigned short* wbfsm = (unsigned short*)(ws + 9846784);   //    8,192 f
    unsigned short* wboff = (unsigned short*)(ws + 9854976);   //   16,384 f
    unsigned short* wbcat = (unsigned short*)(ws + 9871360);   //    4,096 f
    unsigned short* wbdcn = (unsigned short*)(ws + 9875456);   //   36,864 f
    uint4* fsC4  = (uint4*)(ws + 9912320);                     //   524,288 f

    k_prep<<<318, 256, 0, stream>>>(feat_s, fsT4, fsC4, W_fsm, W_off, W_cat,
                                    W_dcn, W_om, wbfsm, wboff, wbcat, wbdcn, wb2);

    k12<<<512, 512, 0, stream>>>(feat_l, fsT4, wbfsm, wboff,
                                 s_fsm, b_fsm, s_off, b_off, feat_arm, offT);
    k_omdcn<<<512, 512, 0, stream>>>(offT, fsC4, wb2, b_om, wbdcn, b_dcn,
                                     wbcat, s_cat, b_cat, feat_arm, feat);
}